// Round 5
// baseline (230.390 us; speedup 1.0000x reference)
//
#include <hip/hip_runtime.h>
#include <math.h>

#define EPSF 1e-6f

typedef __attribute__((ext_vector_type(8))) short bf16x8;
typedef __attribute__((ext_vector_type(4))) float f32x4;
typedef unsigned short u16;
typedef unsigned int u32;

#define MFMA16(a,b,c) __builtin_amdgcn_mfma_f32_16x16x32_bf16((a),(b),(c),0,0,0)

__device__ __forceinline__ float bf2f(u16 u){
  union { u32 i; float f; } x; x.i = ((u32)u)<<16; return x.f;
}
__device__ __forceinline__ u16 f2bf(float f){
  u32 x = __builtin_bit_cast(u32, f);
  u32 r = (x + 0x7fffu + ((x >> 16) & 1u)) >> 16;
  return (u16)r;
}
__device__ __forceinline__ void gll16(const void* g, void* l){
  __builtin_amdgcn_global_load_lds(
      (const __attribute__((address_space(1))) u32*)g,
      (__attribute__((address_space(3))) u32*)l, 16, 0, 0);
}

// ---------------- k0: pack weights to bf16 + zero kv accumulators ---------
__global__ __launch_bounds__(256) void k0_prep(
    const float* __restrict__ wq, const float* __restrict__ bq,
    const float* __restrict__ wk, const float* __restrict__ bk,
    const float* __restrict__ wv, const float* __restrict__ bv,
    const float* __restrict__ wg, const float* __restrict__ bg,
    const float* __restrict__ pw_w, const float* __restrict__ wo,
    u16* __restrict__ wpack, u16* __restrict__ pwb, u16* __restrict__ wob,
    float* __restrict__ bpack, float* __restrict__ kvacc, float* __restrict__ ksumacc)
{
  int idx = blockIdx.x*256 + threadIdx.x;
  const int NW = 1536*384;
  if (idx < NW) {
    int r = idx / 384, c = idx - r*384;
    int h = r / 192, s = (r % 192)/48, d = r % 48;
    const float* w = (s==0)?wq:(s==1)?wk:(s==2)?wv:wg;
    wpack[idx] = f2bf(w[(h*48+d)*384 + c]);
    if (c==0){
      const float* b = (s==0)?bq:(s==1)?bk:(s==2)?bv:bg;
      bpack[r] = b[h*48+d];
    }
  } else if (idx < NW + 147456) {
    pwb[idx - NW] = f2bf(pw_w[idx - NW]);
  } else if (idx < NW + 2*147456) {
    wob[idx - NW - 147456] = f2bf(wo[idx - NW - 147456]);
  } else if (idx < NW + 2*147456 + 147456) {
    kvacc[idx - NW - 2*147456] = 0.f;
  } else if (idx < NW + 2*147456 + 147456 + 3072) {
    ksumacc[idx - NW - 2*147456 - 147456] = 0.f;
  }
}

// ---------------- k1: depthwise 3x3 conv (+dw_b) -> t bf16 ----------------
__global__ __launch_bounds__(256) void k1_dw(
    const float* __restrict__ x, const float* __restrict__ dw_w,
    const float* __restrict__ dw_b, u16* __restrict__ t)
{
  int idx = blockIdx.x*256 + threadIdx.x;   // 786432 threads
  int c4 = idx % 96; int rest = idx / 96;
  int jg = rest & 15; rest >>= 4;
  int i = rest & 63; int b = rest >> 6;
  int c0 = c4*4, j0 = jg*4;
  float wf[36];
  {
    const float4* wp = (const float4*)(dw_w + c0*9);
    #pragma unroll
    for (int k=0;k<9;k++){
      float4 v = wp[k];
      wf[4*k] = v.x; wf[4*k+1] = v.y; wf[4*k+2] = v.z; wf[4*k+3] = v.w;
    }
  }
  float4 bias = *(const float4*)(dw_b + c0);
  float acc[4][4];
  #pragma unroll
  for (int tk=0;tk<4;tk++){
    acc[tk][0]=bias.x; acc[tk][1]=bias.y; acc[tk][2]=bias.z; acc[tk][3]=bias.w;
  }
  const float* xb = x + ((size_t)b<<12)*384;
  #pragma unroll
  for (int di=-1; di<=1; ++di){
    int ii = i+di; if ((unsigned)ii >= 64u) continue;
    #pragma unroll
    for (int dj=-1; dj<=4; ++dj){
      int jj = j0+dj; if ((unsigned)jj >= 64u) continue;
      float4 xv = *(const float4*)(xb + (size_t)((ii<<6)+jj)*384 + c0);
      #pragma unroll
      for (int tk=0;tk<4;tk++){
        const int dd = dj - tk;
        if (dd < -1 || dd > 1) continue;
        const int tap = (di+1)*3 + (dd+1);
        acc[tk][0] = fmaf(xv.x, wf[0*9+tap], acc[tk][0]);
        acc[tk][1] = fmaf(xv.y, wf[1*9+tap], acc[tk][1]);
        acc[tk][2] = fmaf(xv.z, wf[2*9+tap], acc[tk][2]);
        acc[tk][3] = fmaf(xv.w, wf[3*9+tap], acc[tk][3]);
      }
    }
  }
  int mbase = (b<<12) + (i<<6) + j0;
  #pragma unroll
  for (int tk=0;tk<4;tk++){
    ushort4 o; o.x=f2bf(acc[tk][0]); o.y=f2bf(acc[tk][1]);
    o.z=f2bf(acc[tk][2]); o.w=f2bf(acc[tk][3]);
    *(ushort4*)(t + (size_t)(mbase+tk)*384 + c0) = o;
  }
}

// ---------------- k2: xm = bf16( x + t @ pw^T + pw_b ) --------------------
// LDS tiles chunk-major: [8 chunks of 16B][128 rows] -> conflict-free b128.
__global__ __launch_bounds__(256) void k2_gemm_pw(
    const u16* __restrict__ t, const u16* __restrict__ pwb,
    const float* __restrict__ x, const float* __restrict__ pw_b,
    u16* __restrict__ xm)
{
  __shared__ __align__(16) u16 As[128*64];
  __shared__ __align__(16) u16 Bs[128*64];
  const int m0 = blockIdx.x * 128;
  const int n0 = blockIdx.y * 128;
  const int tid = threadIdx.x, w = tid>>6, l = tid&63;
  const int lc = l & 15, hi = l >> 4;
  const f32x4 zf = {0.f,0.f,0.f,0.f};
  f32x4 acc[4][4];
  #pragma unroll
  for (int i=0;i<4;i++)
    #pragma unroll
    for (int j=0;j<4;j++) acc[i][j] = zf;

  for (int k0=0; k0<384; k0+=64) {
    #pragma unroll
    for (int c=0;c<4;c++){
      int chunk = 2*c + (w>>1);
      int row = (w&1)*64 + l;
      gll16((const char*)t   + ((size_t)(m0+row)*384 + k0 + chunk*8)*2, (char*)As + (c*256+w*64)*16);
      gll16((const char*)pwb + ((size_t)(n0+row)*384 + k0 + chunk*8)*2, (char*)Bs + (c*256+w*64)*16);
    }
    __syncthreads();
    const int wr = (w>>1)*64, wc = (w&1)*64;
    #pragma unroll
    for (int kk=0; kk<64; kk+=32){
      const int ca = (kk>>3) + hi;
      bf16x8 a[4], bb[4];
      #pragma unroll
      for (int i=0;i<4;i++) a[i]  = *(const bf16x8*)&As[(ca*128 + wr + i*16 + lc)*8];
      #pragma unroll
      for (int j=0;j<4;j++) bb[j] = *(const bf16x8*)&Bs[(ca*128 + wc + j*16 + lc)*8];
      #pragma unroll
      for (int i=0;i<4;i++)
        #pragma unroll
        for (int j=0;j<4;j++)
          acc[i][j] = MFMA16(a[i], bb[j], acc[i][j]);
    }
    __syncthreads();
  }
  const int wr=(w>>1)*64, wc=(w&1)*64;
  #pragma unroll
  for (int j=0;j<4;j++){
    int n = n0 + wc + j*16 + lc;
    float bias = pw_b[n];
    #pragma unroll
    for (int i=0;i<4;i++)
      #pragma unroll
      for (int r=0;r<4;r++){
        int m = m0 + wr + i*16 + hi*4 + r;
        float v = acc[i][j][r] + x[(size_t)m*384 + n] + bias;
        xm[(size_t)m*384 + n] = f2bf(v);
      }
  }
}

// ---------------- k3: fused QKVG GEMM + activations + kv/ksum accum -------
// As [8][128], Bs [8][192] chunk-major; qh stored chunk-major 48-wide.
__global__ __launch_bounds__(256) void k3_gemm_qkvg(
    const u16* __restrict__ xm, const u16* __restrict__ wpack,
    const float* __restrict__ bpack, const float* __restrict__ temperature,
    u16* __restrict__ qh, float* __restrict__ kvacc, float* __restrict__ ksumacc)
{
  __shared__ __align__(16) u16 smem[20480];
  u16* As = smem;          // 1024 slots
  u16* Bs = smem + 8192;   // 1536 slots
  const int m0 = blockIdx.x * 128;
  const int h  = blockIdx.y;
  const int tid = threadIdx.x, w = tid>>6, l = tid&63;
  const int lc = l & 15, hi = l >> 4;
  const f32x4 zf = {0.f,0.f,0.f,0.f};
  f32x4 acc[2][12];
  #pragma unroll
  for (int i=0;i<2;i++)
    #pragma unroll
    for (int j=0;j<12;j++) acc[i][j] = zf;

  for (int k0=0; k0<384; k0+=64){
    #pragma unroll
    for (int c=0;c<4;c++){
      int chunk = 2*c + (w>>1);
      int row = (w&1)*64 + l;
      gll16((const char*)xm + ((size_t)(m0+row)*384 + k0 + chunk*8)*2, (char*)As + (c*256+w*64)*16);
    }
    #pragma unroll
    for (int c=0;c<6;c++){
      int q = c*4 + w;
      int chunk = q/3;
      int row = (q - chunk*3)*64 + l;
      gll16((const char*)wpack + ((size_t)(h*192+row)*384 + k0 + chunk*8)*2, (char*)Bs + q*1024);
    }
    __syncthreads();
    const int rbase = w*32;
    #pragma unroll
    for (int kk=0; kk<64; kk+=32){
      const int ca = (kk>>3) + hi;
      bf16x8 a0 = *(const bf16x8*)&As[(ca*128 + rbase +      lc)*8];
      bf16x8 a1 = *(const bf16x8*)&As[(ca*128 + rbase + 16 + lc)*8];
      #pragma unroll
      for (int j=0;j<12;j++){
        bf16x8 bb = *(const bf16x8*)&Bs[(ca*192 + j*16 + lc)*8];
        acc[0][j] = MFMA16(a0, bb, acc[0][j]);
        acc[1][j] = MFMA16(a1, bb, acc[1][j]);
      }
    }
    __syncthreads();
  }

  // ---- epilogue ----
  const float tq = temperature[h];
  const int b = m0 >> 12;
  const size_t bh = (size_t)b*8 + h;
  const int bb0 = h*192;
  float biasq[3], biask[3], biasv[3], biasg[3];
  #pragma unroll
  for (int j=0;j<3;j++){
    biasq[j] = bpack[bb0       + j*16 + lc];
    biask[j] = bpack[bb0 + 48  + j*16 + lc];
    biasv[j] = bpack[bb0 + 96  + j*16 + lc];
    biasg[j] = bpack[bb0 + 144 + j*16 + lc];
  }
  u16* kT  = smem;          // [48][136]
  u16* vT  = smem + 6528;   // [48][136]
  u16* qls = smem + 13056;  // [6 chunks][128 rows] x 8 u16 = 6144
  float ksp[3] = {0.f, 0.f, 0.f};

  #pragma unroll
  for (int i=0;i<2;i++){
    ushort4 kst[3], vst[3];
    #pragma unroll
    for (int r=0;r<4;r++){
      int row = w*32 + i*16 + hi*4 + r;
      float q0=(acc[i][0][r]+biasq[0])*tq;
      float q1=(acc[i][1][r]+biasq[1])*tq;
      float q2=(acc[i][2][r]+biasq[2])*tq;
      float mx = fmaxf(q0,fmaxf(q1,q2));
      mx = fmaxf(mx, __shfl_xor(mx,1,64));
      mx = fmaxf(mx, __shfl_xor(mx,2,64));
      mx = fmaxf(mx, __shfl_xor(mx,4,64));
      mx = fmaxf(mx, __shfl_xor(mx,8,64));
      int ro8 = row*8 + (lc&7);
      qls[((lc>>3)  )*1024 + ro8] = f2bf(expf(q0-mx));
      qls[((lc>>3)+2)*1024 + ro8] = f2bf(expf(q1-mx));
      qls[((lc>>3)+4)*1024 + ro8] = f2bf(expf(q2-mx));
      float s0=acc[i][3][r]+biask[0];
      float s1=acc[i][4][r]+biask[1];
      float s2=acc[i][5][r]+biask[2];
      float mk = fmaxf(s0,fmaxf(s1,s2));
      mk = fmaxf(mk, __shfl_xor(mk,1,64));
      mk = fmaxf(mk, __shfl_xor(mk,2,64));
      mk = fmaxf(mk, __shfl_xor(mk,4,64));
      mk = fmaxf(mk, __shfl_xor(mk,8,64));
      float k0e = expf(s0-mk), k1e = expf(s1-mk), k2e = expf(s2-mk);
      ksp[0] += k0e; ksp[1] += k1e; ksp[2] += k2e;
      u16 kq0=f2bf(k0e), kq1=f2bf(k1e), kq2=f2bf(k2e);
      u16 vq[3];
      #pragma unroll
      for (int j=0;j<3;j++){
        float vv = acc[i][6+j][r] + biasv[j];
        float gg = acc[i][9+j][r] + biasg[j];
        float sg = 1.f/(1.f + expf(-gg));
        vq[j] = f2bf(vv*sg);
      }
      if (r==0){ kst[0].x=kq0; kst[1].x=kq1; kst[2].x=kq2; vst[0].x=vq[0]; vst[1].x=vq[1]; vst[2].x=vq[2]; }
      if (r==1){ kst[0].y=kq0; kst[1].y=kq1; kst[2].y=kq2; vst[0].y=vq[0]; vst[1].y=vq[1]; vst[2].y=vq[2]; }
      if (r==2){ kst[0].z=kq0; kst[1].z=kq1; kst[2].z=kq2; vst[0].z=vq[0]; vst[1].z=vq[1]; vst[2].z=vq[2]; }
      if (r==3){ kst[0].w=kq0; kst[1].w=kq1; kst[2].w=kq2; vst[0].w=vq[0]; vst[1].w=vq[1]; vst[2].w=vq[2]; }
    }
    int mb = w*32 + i*16 + hi*4;
    #pragma unroll
    for (int j=0;j<3;j++){
      *(ushort4*)&kT[(j*16+lc)*136 + mb] = kst[j];
      *(ushort4*)&vT[(j*16+lc)*136 + mb] = vst[j];
    }
  }
  __syncthreads();

  // coalesced qh store: global layout [bh][tile16][6 chunks][256 rows] x 16B
  {
    const int tile = (m0 & 4095) >> 8;
    const int half = (m0 >> 7) & 1;
    size_t gqb = ((size_t)bh*4096 + tile*256)*48;
    #pragma unroll
    for (int it=0; it<3; ++it){
      int s = it*256 + tid;
      int g = (s>>7)*256 + half*128 + (s&127);
      *(uint4*)(qh + gqb + (size_t)g*8) = *(const uint4*)&qls[s*8];
    }
  }

  // ---- kv partial via MFMA: wave w covers its own 32 tokens ----
  bf16x8 af[3], bfv[3];
  #pragma unroll
  for (int da=0;da<3;da++) af[da]  = *(const bf16x8*)&kT[(da*16+lc)*136 + w*32 + hi*8];
  #pragma unroll
  for (int eb=0;eb<3;eb++) bfv[eb] = *(const bf16x8*)&vT[(eb*16+lc)*136 + w*32 + hi*8];
  f32x4 a2[3][3];
  #pragma unroll
  for (int da=0;da<3;da++)
    #pragma unroll
    for (int eb=0;eb<3;eb++)
      a2[da][eb] = MFMA16(af[da], bfv[eb], zf);
  __syncthreads();
  float* pb = (float*)smem + w*2304;
  #pragma unroll
  for (int da=0;da<3;da++)
    #pragma unroll
    for (int eb=0;eb<3;eb++)
      #pragma unroll
      for (int rr=0;rr<4;rr++)
        pb[(da*16 + hi*4 + rr)*48 + eb*16 + lc] = a2[da][eb][rr];
  __syncthreads();
  float* p0 = (float*)smem;
  for (int u=tid; u<2304; u+=256){
    float s = p0[u] + p0[2304+u] + p0[4608+u] + p0[6912+u];
    atomicAdd(kvacc + bh*2304 + u, s);
  }
  #pragma unroll
  for (int j=0;j<3;j++){
    ksp[j] += __shfl_xor(ksp[j],16,64);
    ksp[j] += __shfl_xor(ksp[j],32,64);
  }
  if (hi==0){
    atomicAdd(ksumacc + bh*48 +      lc, ksp[0]);
    atomicAdd(ksumacc + bh*48 + 16 + lc, ksp[1]);
    atomicAdd(ksumacc + bh*48 + 32 + lc, ksp[2]);
  }
}

// ---------------- k5: kvacc/ksumacc -> kvp chunk-major [bh][8][64] --------
__global__ __launch_bounds__(256) void k5_red(
    const float* __restrict__ kvacc, const float* __restrict__ ksumacc,
    u16* __restrict__ kvp)
{
  int bh = blockIdx.x, tid = threadIdx.x;
  for (int u=tid; u<4096; u+=256){
    int e = u >> 6, d = u & 63;
    float v = 0.f;
    if (e < 48 && d < 48)       v = kvacc[(size_t)bh*2304 + d*48 + e];
    else if (e == 48 && d < 48) v = ksumacc[bh*48 + d];
    kvp[(size_t)bh*4096 + (d>>3)*512 + e*8 + (d&7)] = f2bf(v);
  }
}

// ---------------- k6: num/den -> a_hat bf16 [B,N,C] -----------------------
// As [8][256] chunk-major (linear copy from chunk-major qh; chunks 6,7 zero);
// Bs [8][64] chunk-major (linear copy from chunk-major kvp).
__global__ __launch_bounds__(256) void k6_num(
    const u16* __restrict__ qh, const u16* __restrict__ kvp, u16* __restrict__ ah)
{
  __shared__ __align__(16) u16 As[256*64]; // 2048 slots
  __shared__ __align__(16) u16 Bs[64*64];  // 512 slots
  const int bh = blockIdx.x >> 4, nc = blockIdx.x & 15;
  const int tid = threadIdx.x, w = tid>>6, l = tid&63;
  const int lc = l & 15, hi = l >> 4;
  const f32x4 zf = {0.f,0.f,0.f,0.f};
  const uint4* ga = (const uint4*)(qh + ((size_t)bh*4096 + nc*256)*48);
  #pragma unroll
  for (int it=0; it<6; ++it) ((uint4*)As)[it*256+tid] = ga[it*256+tid];
  uint4 z4 = {0,0,0,0};
  *(uint4*)&As[(1536+tid)*8] = z4;
  *(uint4*)&As[(1792+tid)*8] = z4;
  const uint4* gb = (const uint4*)(kvp + (size_t)bh*4096);
  #pragma unroll
  for (int it=0; it<2; ++it) ((uint4*)Bs)[it*256+tid] = gb[it*256+tid];
  __syncthreads();
  f32x4 acc[4][4];
  #pragma unroll
  for (int i=0;i<4;i++)
    #pragma unroll
    for (int j=0;j<4;j++) acc[i][j] = zf;
  const int rbase = w*64;
  #pragma unroll
  for (int kk=0; kk<64; kk+=32){
    const int ca = (kk>>3) + hi;
    bf16x8 a[4], bb[4];
    #pragma unroll
    for (int i=0;i<4;i++) a[i]  = *(const bf16x8*)&As[(ca*256 + rbase + i*16 + lc)*8];
    #pragma unroll
    for (int j=0;j<4;j++) bb[j] = *(const bf16x8*)&Bs[(ca*64 + j*16 + lc)*8];
    #pragma unroll
    for (int i=0;i<4;i++)
      #pragma unroll
      for (int j=0;j<4;j++)
        acc[i][j] = MFMA16(a[i], bb[j], acc[i][j]);
  }
  const int b = bh >> 3, h = bh & 7;
  #pragma unroll
  for (int i=0;i<4;i++){
    #pragma unroll
    for (int r=0;r<4;r++){
      float den = __shfl(acc[i][3][r], l & 48, 64) + EPSF;  // e=48 = q . ksum
      float rd = 1.f/den;
      int n = nc*256 + rbase + i*16 + hi*4 + r;
      size_t ob = ((size_t)b*4096 + n)*384 + h*48;
      ah[ob +      lc] = f2bf(acc[i][0][r]*rd);
      ah[ob + 16 + lc] = f2bf(acc[i][1][r]*rd);
      ah[ob + 32 + lc] = f2bf(acc[i][2][r]*rd);
    }
  }
}

// ---------------- k7: out = a_hat @ wo^T + bo (fp32) ----------------------
__global__ __launch_bounds__(256) void k7_gemm_out(
    const u16* __restrict__ ah, const u16* __restrict__ wob,
    const float* __restrict__ bo, float* __restrict__ out)
{
  __shared__ __align__(16) u16 As[128*64];
  __shared__ __align__(16) u16 Bs[128*64];
  const int m0 = blockIdx.x * 128;
  const int n0 = blockIdx.y * 128;
  const int tid = threadIdx.x, w = tid>>6, l = tid&63;
  const int lc = l & 15, hi = l >> 4;
  const f32x4 zf = {0.f,0.f,0.f,0.f};
  f32x4 acc[4][4];
  #pragma unroll
  for (int i=0;i<4;i++)
    #pragma unroll
    for (int j=0;j<4;j++) acc[i][j] = zf;

  for (int k0=0; k0<384; k0+=64) {
    #pragma unroll
    for (int c=0;c<4;c++){
      int chunk = 2*c + (w>>1);
      int row = (w&1)*64 + l;
      gll16((const char*)ah  + ((size_t)(m0+row)*384 + k0 + chunk*8)*2, (char*)As + (c*256+w*64)*16);
      gll16((const char*)wob + ((size_t)(n0+row)*384 + k0 + chunk*8)*2, (char*)Bs + (c*256+w*64)*16);
    }
    __syncthreads();
    const int wr = (w>>1)*64, wc = (w&1)*64;
    #pragma unroll
    for (int kk=0; kk<64; kk+=32){
      const int ca = (kk>>3) + hi;
      bf16x8 a[4], bb[4];
      #pragma unroll
      for (int i=0;i<4;i++) a[i]  = *(const bf16x8*)&As[(ca*128 + wr + i*16 + lc)*8];
      #pragma unroll
      for (int j=0;j<4;j++) bb[j] = *(const bf16x8*)&Bs[(ca*128 + wc + j*16 + lc)*8];
      #pragma unroll
      for (int i=0;i<4;i++)
        #pragma unroll
        for (int j=0;j<4;j++)
          acc[i][j] = MFMA16(a[i], bb[j], acc[i][j]);
    }
    __syncthreads();
  }
  const int wr=(w>>1)*64, wc=(w&1)*64;
  #pragma unroll
  for (int j=0;j<4;j++){
    int n = n0 + wc + j*16 + lc;
    float bias = bo[n];
    #pragma unroll
    for (int i=0;i<4;i++)
      #pragma unroll
      for (int r=0;r<4;r++){
        int m = m0 + wr + i*16 + hi*4 + r;
        out[(size_t)m*384 + n] = acc[i][j][r] + bias;
      }
  }
}

extern "C" void kernel_launch(void* const* d_in, const int* in_sizes, int n_in,
                              void* d_out, int out_size, void* d_ws, size_t ws_size,
                              hipStream_t stream)
{
  const float* x    = (const float*)d_in[0];
  const float* wq   = (const float*)d_in[1];
  const float* bq   = (const float*)d_in[2];
  const float* wk   = (const float*)d_in[3];
  const float* bk   = (const float*)d_in[4];
  const float* wv   = (const float*)d_in[5];
  const float* bv   = (const float*)d_in[6];
  const float* wg   = (const float*)d_in[7];
  const float* bg   = (const float*)d_in[8];
  const float* wo   = (const float*)d_in[9];
  const float* bo   = (const float*)d_in[10];
  const float* temp = (const float*)d_in[11];
  const float* dw_w = (const float*)d_in[12];
  const float* dw_b = (const float*)d_in[13];
  const float* pw_w = (const float*)d_in[14];
  const float* pw_b = (const float*)d_in[15];
  float* out = (float*)d_out;
  char* ws = (char*)d_ws;

  u16*   t       = (u16*)(ws + 0);            // 25165824 ; reused as a_hat
  u16*   xm      = (u16*)(ws + 25165824);     // 25165824
  u16*   qh      = (u16*)(ws + 50331648);     // 25165824 used  [bh][tile][6][256]x16B
  u16*   wpack   = (u16*)(ws + 83886080);     // 1179648
  u16*   pwb     = (u16*)(ws + 85065728);     // 294912
  u16*   wob     = (u16*)(ws + 85360640);     // 294912
  float* bpack   = (float*)(ws + 85655552);   // 6144
  float* kvacc   = (float*)(ws + 85661696);   // 589824  [64][48][48] f32
  float* ksumacc = (float*)(ws + 86251520);   // 12288   [64][48] f32
  u16*   kvp     = (u16*)(ws + 86263808);     // 524288  [64][8][64]x16B bf16

  k0_prep<<<4044, 256, 0, stream>>>(wq,bq,wk,bk,wv,bv,wg,bg,pw_w,wo,
                                    wpack,pwb,wob,bpack,kvacc,ksumacc);
  k1_dw<<<3072, 256, 0, stream>>>(x, dw_w, dw_b, t);
  k2_gemm_pw<<<dim3(256,3), 256, 0, stream>>>(t, pwb, x, pw_b, xm);
  k3_gemm_qkvg<<<dim3(256,8), 256, 0, stream>>>(xm, wpack, bpack, temp, qh, kvacc, ksumacc);
  k5_red<<<64, 256, 0, stream>>>(kvacc, ksumacc, kvp);
  k6_num<<<1024, 256, 0, stream>>>(qh, kvp, t /*a_hat*/);
  k7_gemm_out<<<dim3(256,3), 256, 0, stream>>>(t, wob, bo, out);
}

// Round 6
// 223.405 us; speedup vs baseline: 1.0313x; 1.0313x over previous
//
#include <hip/hip_runtime.h>
#include <math.h>

#define EPSF 1e-6f

typedef __attribute__((ext_vector_type(8))) short bf16x8;
typedef __attribute__((ext_vector_type(4))) float f32x4;
typedef unsigned short u16;
typedef unsigned int u32;

#define MFMA16(a,b,c) __builtin_amdgcn_mfma_f32_16x16x32_bf16((a),(b),(c),0,0,0)

__device__ __forceinline__ u16 f2bf(float f){
  u32 x = __builtin_bit_cast(u32, f);
  u32 r = (x + 0x7fffu + ((x >> 16) & 1u)) >> 16;
  return (u16)r;
}
__device__ __forceinline__ void gll16(const void* g, void* l){
  __builtin_amdgcn_global_load_lds(
      (const __attribute__((address_space(1))) u32*)g,
      (__attribute__((address_space(3))) u32*)l, 16, 0, 0);
}

// ---------------- k0: pack weights to bf16 + zero kv accumulators ---------
__global__ __launch_bounds__(256) void k0_prep(
    const float* __restrict__ wq, const float* __restrict__ bq,
    const float* __restrict__ wk, const float* __restrict__ bk,
    const float* __restrict__ wv, const float* __restrict__ bv,
    const float* __restrict__ wg, const float* __restrict__ bg,
    const float* __restrict__ pw_w, const float* __restrict__ wo,
    u16* __restrict__ wpack, u16* __restrict__ pwb, u16* __restrict__ wob,
    float* __restrict__ bpack, float* __restrict__ kvacc, float* __restrict__ ksumacc)
{
  int idx = blockIdx.x*256 + threadIdx.x;
  const int NW = 1536*384;
  if (idx < NW) {
    int r = idx / 384, c = idx - r*384;
    int h = r / 192, s = (r % 192)/48, d = r % 48;
    const float* w = (s==0)?wq:(s==1)?wk:(s==2)?wv:wg;
    wpack[idx] = f2bf(w[(h*48+d)*384 + c]);
    if (c==0){
      const float* b = (s==0)?bq:(s==1)?bk:(s==2)?bv:bg;
      bpack[r] = b[h*48+d];
    }
  } else if (idx < NW + 147456) {
    pwb[idx - NW] = f2bf(pw_w[idx - NW]);
  } else if (idx < NW + 2*147456) {
    wob[idx - NW - 147456] = f2bf(wo[idx - NW - 147456]);
  } else if (idx < NW + 2*147456 + 147456) {
    kvacc[idx - NW - 2*147456] = 0.f;
  } else if (idx < NW + 2*147456 + 147456 + 3072) {
    ksumacc[idx - NW - 2*147456 - 147456] = 0.f;
  }
}

// ---------------- k1: depthwise 3x3 conv (+dw_b) -> t bf16 ----------------
__global__ __launch_bounds__(256) void k1_dw(
    const float* __restrict__ x, const float* __restrict__ dw_w,
    const float* __restrict__ dw_b, u16* __restrict__ t)
{
  int idx = blockIdx.x*256 + threadIdx.x;   // 786432 threads
  int c4 = idx % 96; int rest = idx / 96;
  int jg = rest & 15; rest >>= 4;
  int i = rest & 63; int b = rest >> 6;
  int c0 = c4*4, j0 = jg*4;
  float wf[36];
  {
    const float4* wp = (const float4*)(dw_w + c0*9);
    #pragma unroll
    for (int k=0;k<9;k++){
      float4 v = wp[k];
      wf[4*k] = v.x; wf[4*k+1] = v.y; wf[4*k+2] = v.z; wf[4*k+3] = v.w;
    }
  }
  float4 bias = *(const float4*)(dw_b + c0);
  float acc[4][4];
  #pragma unroll
  for (int tk=0;tk<4;tk++){
    acc[tk][0]=bias.x; acc[tk][1]=bias.y; acc[tk][2]=bias.z; acc[tk][3]=bias.w;
  }
  const float* xb = x + ((size_t)b<<12)*384;
  #pragma unroll
  for (int di=-1; di<=1; ++di){
    int ii = i+di; if ((unsigned)ii >= 64u) continue;
    #pragma unroll
    for (int dj=-1; dj<=4; ++dj){
      int jj = j0+dj; if ((unsigned)jj >= 64u) continue;
      float4 xv = *(const float4*)(xb + (size_t)((ii<<6)+jj)*384 + c0);
      #pragma unroll
      for (int tk=0;tk<4;tk++){
        const int dd = dj - tk;
        if (dd < -1 || dd > 1) continue;
        const int tap = (di+1)*3 + (dd+1);
        acc[tk][0] = fmaf(xv.x, wf[0*9+tap], acc[tk][0]);
        acc[tk][1] = fmaf(xv.y, wf[1*9+tap], acc[tk][1]);
        acc[tk][2] = fmaf(xv.z, wf[2*9+tap], acc[tk][2]);
        acc[tk][3] = fmaf(xv.w, wf[3*9+tap], acc[tk][3]);
      }
    }
  }
  int mbase = (b<<12) + (i<<6) + j0;
  #pragma unroll
  for (int tk=0;tk<4;tk++){
    ushort4 o; o.x=f2bf(acc[tk][0]); o.y=f2bf(acc[tk][1]);
    o.z=f2bf(acc[tk][2]); o.w=f2bf(acc[tk][3]);
    *(ushort4*)(t + (size_t)(mbase+tk)*384 + c0) = o;
  }
}

// ---------------- k2: xm = bf16( x + t @ pw^T + pw_b )  [R4 version] ------
__global__ __launch_bounds__(256) void k2_gemm_pw(
    const u16* __restrict__ t, const u16* __restrict__ pwb,
    const float* __restrict__ x, const float* __restrict__ pw_b,
    u16* __restrict__ xm)
{
  __shared__ __align__(16) u16 As[128*64];
  __shared__ __align__(16) u16 Bs[128*64];
  const int m0 = blockIdx.x * 128;
  const int n0 = blockIdx.y * 128;
  const int tid = threadIdx.x, w = tid>>6, l = tid&63;
  const f32x4 zf = {0.f,0.f,0.f,0.f};
  f32x4 acc[4][4];
  #pragma unroll
  for (int i=0;i<4;i++)
    #pragma unroll
    for (int j=0;j<4;j++) acc[i][j] = zf;

  for (int k0=0; k0<384; k0+=64) {
    #pragma unroll
    for (int i=0;i<4;i++){
      int ch = w*4+i;
      int row = ch*8 + (l>>3);
      gll16((const char*)t   + ((size_t)(m0+row)*384 + k0)*2 + (l&7)*16, (char*)As + ch*1024);
      gll16((const char*)pwb + ((size_t)(n0+row)*384 + k0)*2 + (l&7)*16, (char*)Bs + ch*1024);
    }
    __syncthreads();
    const int wr = (w>>1)*64, wc = (w&1)*64;
    #pragma unroll
    for (int kk=0; kk<64; kk+=32){
      bf16x8 a[4], bb[4];
      #pragma unroll
      for (int i=0;i<4;i++) a[i]  = *(const bf16x8*)&As[(wr + i*16 + (l&15))*64 + kk + (l>>4)*8];
      #pragma unroll
      for (int j=0;j<4;j++) bb[j] = *(const bf16x8*)&Bs[(wc + j*16 + (l&15))*64 + kk + (l>>4)*8];
      #pragma unroll
      for (int i=0;i<4;i++)
        #pragma unroll
        for (int j=0;j<4;j++)
          acc[i][j] = MFMA16(a[i], bb[j], acc[i][j]);
    }
    __syncthreads();
  }
  const int wr=(w>>1)*64, wc=(w&1)*64;
  #pragma unroll
  for (int j=0;j<4;j++){
    int n = n0 + wc + j*16 + (l&15);
    float bias = pw_b[n];
    #pragma unroll
    for (int i=0;i<4;i++)
      #pragma unroll
      for (int r=0;r<4;r++){
        int m = m0 + wr + i*16 + (l>>4)*4 + r;
        float v = acc[i][j][r] + x[(size_t)m*384 + n] + bias;
        xm[(size_t)m*384 + n] = f2bf(v);
      }
  }
}

// ---------------- k3: QKVG GEMM, 256-token tile, 16 waves, dbuf prefetch --
// LDS 112KB: A dbuf 2x32KB (XOR-swizzled chunks), B dbuf 2x24KB.
__global__ __launch_bounds__(1024, 4) void k3_gemm_qkvg(
    const u16* __restrict__ xm, const u16* __restrict__ wpack,
    const float* __restrict__ bpack, const float* __restrict__ temperature,
    u16* __restrict__ qh, float* __restrict__ kvacc, float* __restrict__ ksumacc)
{
  __shared__ __align__(16) u16 smem[57344];   // 112KB
  const int m0 = blockIdx.x * 256;
  const int h  = blockIdx.y;
  const int tid = threadIdx.x, w = tid>>6, l = tid&63;
  const int lc = l & 15, hi = l >> 4;
  const f32x4 zf = {0.f,0.f,0.f,0.f};
  f32x4 acc[12];
  #pragma unroll
  for (int j=0;j<12;j++) acc[j] = zf;

  // ---- staging: linear LDS dest, XOR-pre-swizzled global source ----
  #define K3_STAGE(T, CUR) do {                                               \
    const int k0_ = (T)*64;                                                   \
    u16* Ab_ = smem + (CUR)*16384;                                            \
    u16* Bb_ = smem + 32768 + (CUR)*12288;                                    \
    _Pragma("unroll")                                                         \
    for (int c=0;c<2;c++){                                                    \
      int ci = c*1024 + tid;                                                  \
      int R = ci>>3, osw = (ci&7) ^ (R&7);                                    \
      gll16((const char*)xm + ((size_t)(m0+R)*384 + k0_)*2 + osw*16,          \
            (char*)Ab_ + (c*1024 + w*64)*16);                                 \
    }                                                                         \
    {                                                                         \
      int ci = tid;                                                           \
      int R = ci>>3, osw = (ci&7) ^ (R&7);                                    \
      gll16((const char*)wpack + ((size_t)(h*192+R)*384 + k0_)*2 + osw*16,    \
            (char*)Bb_ + (w*64)*16);                                          \
    }                                                                         \
    if (tid < 512){                                                           \
      int ci = 1024 + tid;                                                    \
      int R = ci>>3, osw = (ci&7) ^ (R&7);                                    \
      gll16((const char*)wpack + ((size_t)(h*192+R)*384 + k0_)*2 + osw*16,    \
            (char*)Bb_ + (1024 + w*64)*16);                                   \
    }                                                                         \
  } while(0)

  K3_STAGE(0, 0);
  __syncthreads();
  int cur = 0;
  const int rbase = w*16;
  for (int t=0; t<6; ++t){
    if (t < 5) K3_STAGE(t+1, cur^1);
    const u16* Ab = smem + cur*16384;
    const u16* Bb = smem + 32768 + cur*12288;
    #pragma unroll
    for (int kk=0; kk<64; kk+=32){
      const int ca = (kk>>3) + hi;
      const int sw = ca ^ (lc&7);
      bf16x8 a0 = *(const bf16x8*)&Ab[((rbase+lc)*8 + sw)*8];
      #pragma unroll
      for (int j=0;j<12;j++){
        bf16x8 bb = *(const bf16x8*)&Bb[((j*16+lc)*8 + sw)*8];
        acc[j] = MFMA16(a0, bb, acc[j]);
      }
    }
    __syncthreads();
    cur ^= 1;
  }

  // ---- epilogue ----
  const float tq = temperature[h];
  const int b = m0 >> 12;
  const size_t bh = (size_t)b*8 + h;
  const int bb0 = h*192;
  float biasq[3], biask[3], biasv[3], biasg[3];
  #pragma unroll
  for (int j=0;j<3;j++){
    biasq[j] = bpack[bb0       + j*16 + lc];
    biask[j] = bpack[bb0 + 48  + j*16 + lc];
    biasv[j] = bpack[bb0 + 96  + j*16 + lc];
    biasg[j] = bpack[bb0 + 144 + j*16 + lc];
  }
  u16* qls = smem;            // [6][256][8] u16 = 12288
  u16* vT  = smem + 12288;    // [48][264]   = 12672
  u16* kT  = smem + 32768;    // [48][264]
  float ksp[3] = {0.f, 0.f, 0.f};

  {
    ushort4 kst[3], vst[3];
    #pragma unroll
    for (int r=0;r<4;r++){
      int row = w*16 + hi*4 + r;
      float q0=(acc[0][r]+biasq[0])*tq;
      float q1=(acc[1][r]+biasq[1])*tq;
      float q2=(acc[2][r]+biasq[2])*tq;
      float mx = fmaxf(q0,fmaxf(q1,q2));
      mx = fmaxf(mx, __shfl_xor(mx,1,64));
      mx = fmaxf(mx, __shfl_xor(mx,2,64));
      mx = fmaxf(mx, __shfl_xor(mx,4,64));
      mx = fmaxf(mx, __shfl_xor(mx,8,64));
      int p8 = row*8 + (lc&7);
      qls[(lc>>3)*2048     + p8] = f2bf(expf(q0-mx));
      qls[((lc>>3)+2)*2048 + p8] = f2bf(expf(q1-mx));
      qls[((lc>>3)+4)*2048 + p8] = f2bf(expf(q2-mx));
      float s0=acc[3][r]+biask[0];
      float s1=acc[4][r]+biask[1];
      float s2=acc[5][r]+biask[2];
      float mk = fmaxf(s0,fmaxf(s1,s2));
      mk = fmaxf(mk, __shfl_xor(mk,1,64));
      mk = fmaxf(mk, __shfl_xor(mk,2,64));
      mk = fmaxf(mk, __shfl_xor(mk,4,64));
      mk = fmaxf(mk, __shfl_xor(mk,8,64));
      float k0e = expf(s0-mk), k1e = expf(s1-mk), k2e = expf(s2-mk);
      ksp[0] += k0e; ksp[1] += k1e; ksp[2] += k2e;
      u16 kq0=f2bf(k0e), kq1=f2bf(k1e), kq2=f2bf(k2e);
      u16 vq[3];
      #pragma unroll
      for (int j=0;j<3;j++){
        float vv = acc[6+j][r] + biasv[j];
        float gg = acc[9+j][r] + biasg[j];
        float sg = 1.f/(1.f + expf(-gg));
        vq[j] = f2bf(vv*sg);
      }
      if (r==0){ kst[0].x=kq0; kst[1].x=kq1; kst[2].x=kq2; vst[0].x=vq[0]; vst[1].x=vq[1]; vst[2].x=vq[2]; }
      if (r==1){ kst[0].y=kq0; kst[1].y=kq1; kst[2].y=kq2; vst[0].y=vq[0]; vst[1].y=vq[1]; vst[2].y=vq[2]; }
      if (r==2){ kst[0].z=kq0; kst[1].z=kq1; kst[2].z=kq2; vst[0].z=vq[0]; vst[1].z=vq[1]; vst[2].z=vq[2]; }
      if (r==3){ kst[0].w=kq0; kst[1].w=kq1; kst[2].w=kq2; vst[0].w=vq[0]; vst[1].w=vq[1]; vst[2].w=vq[2]; }
    }
    int mb = w*16 + hi*4;
    #pragma unroll
    for (int j=0;j<3;j++){
      *(ushort4*)&kT[(j*16+lc)*264 + mb] = kst[j];
      *(ushort4*)&vT[(j*16+lc)*264 + mb] = vst[j];
    }
  }
  __syncthreads();

  // qh store: row-major [bh][n][64], chunks 6,7 zero
  {
    size_t gqb = ((size_t)bh*4096 + (m0 & 4095))*64;
    #pragma unroll
    for (int it=0; it<2; ++it){
      int idx = it*1024 + tid;
      int row = idx>>3, ch = idx&7;
      uint4 v = {0,0,0,0};
      if (ch < 6) v = *(const uint4*)&qls[ch*2048 + row*8];
      *(uint4*)(qh + gqb + (size_t)row*64 + ch*8) = v;
    }
  }

  // kv partial via MFMA: waves 0..7 each cover 32 tokens
  f32x4 a2[3][3];
  if (w < 8){
    bf16x8 af[3], bfv[3];
    #pragma unroll
    for (int da=0;da<3;da++) af[da]  = *(const bf16x8*)&kT[(da*16+lc)*264 + w*32 + hi*8];
    #pragma unroll
    for (int eb=0;eb<3;eb++) bfv[eb] = *(const bf16x8*)&vT[(eb*16+lc)*264 + w*32 + hi*8];
    #pragma unroll
    for (int da=0;da<3;da++)
      #pragma unroll
      for (int eb=0;eb<3;eb++)
        a2[da][eb] = MFMA16(af[da], bfv[eb], zf);
  }
  __syncthreads();
  if (w < 8){
    float* pb = (w<4) ? ((float*)smem + w*2304)
                      : ((float*)(smem + 32768) + (w-4)*2304);
    #pragma unroll
    for (int da=0;da<3;da++)
      #pragma unroll
      for (int eb=0;eb<3;eb++)
        #pragma unroll
        for (int rr=0;rr<4;rr++)
          pb[(da*16 + hi*4 + rr)*48 + eb*16 + lc] = a2[da][eb][rr];
  }
  __syncthreads();
  {
    float* pA = (float*)smem;
    float* pB = (float*)(smem + 32768);
    for (int u=tid; u<2304; u+=1024){
      float s = pA[u] + pA[2304+u] + pA[4608+u] + pA[6912+u]
              + pB[u] + pB[2304+u] + pB[4608+u] + pB[6912+u];
      atomicAdd(kvacc + bh*2304 + u, s);
    }
  }
  #pragma unroll
  for (int j=0;j<3;j++){
    ksp[j] += __shfl_xor(ksp[j],16,64);
    ksp[j] += __shfl_xor(ksp[j],32,64);
  }
  if (hi==0){
    atomicAdd(ksumacc + bh*48 +      lc, ksp[0]);
    atomicAdd(ksumacc + bh*48 + 16 + lc, ksp[1]);
    atomicAdd(ksumacc + bh*48 + 32 + lc, ksp[2]);
  }
  #undef K3_STAGE
}

// ---------------- k5: kvacc/ksumacc -> kvp[e][d] bf16 (64x64, ksum row48) -
__global__ __launch_bounds__(256) void k5_red(
    const float* __restrict__ kvacc, const float* __restrict__ ksumacc,
    u16* __restrict__ kvp)
{
  int bh = blockIdx.x, tid = threadIdx.x;
  for (int u=tid; u<4096; u+=256){
    int e = u >> 6, d = u & 63;
    float v = 0.f;
    if (e < 48 && d < 48)       v = kvacc[(size_t)bh*2304 + d*48 + e];
    else if (e == 48 && d < 48) v = ksumacc[bh*48 + d];
    kvp[((size_t)bh*64 + e)*64 + d] = f2bf(v);
  }
}

// ---------------- k6: num/den -> a_hat bf16 [B,N,C]  [R4 version] ---------
__global__ __launch_bounds__(256) void k6_num(
    const u16* __restrict__ qh, const u16* __restrict__ kvp, u16* __restrict__ ah)
{
  __shared__ __align__(16) u16 As[256*64]; // 32KB
  __shared__ __align__(16) u16 Bs[64*64];  // 8KB
  const int bh = blockIdx.x >> 4, nc = blockIdx.x & 15;
  const int tid = threadIdx.x, w = tid>>6, l = tid&63;
  const f32x4 zf = {0.f,0.f,0.f,0.f};
  const uint4* ga = (const uint4*)(qh + ((size_t)bh*4096 + nc*256)*64);
  #pragma unroll
  for (int it=0; it<8; ++it) ((uint4*)As)[it*256+tid] = ga[it*256+tid];
  const uint4* gb = (const uint4*)(kvp + (size_t)bh*4096);
  #pragma unroll
  for (int it=0; it<2; ++it) ((uint4*)Bs)[it*256+tid] = gb[it*256+tid];
  __syncthreads();
  f32x4 acc[4][4];
  #pragma unroll
  for (int i=0;i<4;i++)
    #pragma unroll
    for (int j=0;j<4;j++) acc[i][j] = zf;
  const int rbase = w*64;
  #pragma unroll
  for (int kk=0; kk<64; kk+=32){
    bf16x8 a[4], bb[4];
    #pragma unroll
    for (int i=0;i<4;i++) a[i]  = *(const bf16x8*)&As[(rbase + i*16 + (l&15))*64 + kk + (l>>4)*8];
    #pragma unroll
    for (int j=0;j<4;j++) bb[j] = *(const bf16x8*)&Bs[(j*16 + (l&15))*64 + kk + (l>>4)*8];
    #pragma unroll
    for (int i=0;i<4;i++)
      #pragma unroll
      for (int j=0;j<4;j++)
        acc[i][j] = MFMA16(a[i], bb[j], acc[i][j]);
  }
  const int b = bh >> 3, h = bh & 7;
  #pragma unroll
  for (int i=0;i<4;i++){
    #pragma unroll
    for (int r=0;r<4;r++){
      float den = __shfl(acc[i][3][r], l & 48, 64) + EPSF;
      float rd = 1.f/den;
      int n = nc*256 + rbase + i*16 + (l>>4)*4 + r;
      size_t ob = ((size_t)b*4096 + n)*384 + h*48;
      ah[ob +      (l&15)] = f2bf(acc[i][0][r]*rd);
      ah[ob + 16 + (l&15)] = f2bf(acc[i][1][r]*rd);
      ah[ob + 32 + (l&15)] = f2bf(acc[i][2][r]*rd);
    }
  }
}

// ---------------- k7: out = a_hat @ wo^T + bo (fp32)  [R4 version] --------
__global__ __launch_bounds__(256) void k7_gemm_out(
    const u16* __restrict__ ah, const u16* __restrict__ wob,
    const float* __restrict__ bo, float* __restrict__ out)
{
  __shared__ __align__(16) u16 As[128*64];
  __shared__ __align__(16) u16 Bs[128*64];
  const int m0 = blockIdx.x * 128;
  const int n0 = blockIdx.y * 128;
  const int tid = threadIdx.x, w = tid>>6, l = tid&63;
  const f32x4 zf = {0.f,0.f,0.f,0.f};
  f32x4 acc[4][4];
  #pragma unroll
  for (int i=0;i<4;i++)
    #pragma unroll
    for (int j=0;j<4;j++) acc[i][j] = zf;

  for (int k0=0; k0<384; k0+=64) {
    #pragma unroll
    for (int i=0;i<4;i++){
      int ch = w*4+i;
      int row = ch*8 + (l>>3);
      gll16((const char*)ah  + ((size_t)(m0+row)*384 + k0)*2 + (l&7)*16, (char*)As + ch*1024);
      gll16((const char*)wob + ((size_t)(n0+row)*384 + k0)*2 + (l&7)*16, (char*)Bs + ch*1024);
    }
    __syncthreads();
    const int wr = (w>>1)*64, wc = (w&1)*64;
    #pragma unroll
    for (int kk=0; kk<64; kk+=32){
      bf16x8 a[4], bb[4];
      #pragma unroll
      for (int i=0;i<4;i++) a[i]  = *(const bf16x8*)&As[(wr + i*16 + (l&15))*64 + kk + (l>>4)*8];
      #pragma unroll
      for (int j=0;j<4;j++) bb[j] = *(const bf16x8*)&Bs[(wc + j*16 + (l&15))*64 + kk + (l>>4)*8];
      #pragma unroll
      for (int i=0;i<4;i++)
        #pragma unroll
        for (int j=0;j<4;j++)
          acc[i][j] = MFMA16(a[i], bb[j], acc[i][j]);
    }
    __syncthreads();
  }
  const int wr=(w>>1)*64, wc=(w&1)*64;
  #pragma unroll
  for (int j=0;j<4;j++){
    int n = n0 + wc + j*16 + (l&15);
    float bias = bo[n];
    #pragma unroll
    for (int i=0;i<4;i++)
      #pragma unroll
      for (int r=0;r<4;r++){
        int m = m0 + wr + i*16 + (l>>4)*4 + r;
        out[(size_t)m*384 + n] = acc[i][j][r] + bias;
      }
  }
}

extern "C" void kernel_launch(void* const* d_in, const int* in_sizes, int n_in,
                              void* d_out, int out_size, void* d_ws, size_t ws_size,
                              hipStream_t stream)
{
  const float* x    = (const float*)d_in[0];
  const float* wq   = (const float*)d_in[1];
  const float* bq   = (const float*)d_in[2];
  const float* wk   = (const float*)d_in[3];
  const float* bk   = (const float*)d_in[4];
  const float* wv   = (const float*)d_in[5];
  const float* bv   = (const float*)d_in[6];
  const float* wg   = (const float*)d_in[7];
  const float* bg   = (const float*)d_in[8];
  const float* wo   = (const float*)d_in[9];
  const float* bo   = (const float*)d_in[10];
  const float* temp = (const float*)d_in[11];
  const float* dw_w = (const float*)d_in[12];
  const float* dw_b = (const float*)d_in[13];
  const float* pw_w = (const float*)d_in[14];
  const float* pw_b = (const float*)d_in[15];
  float* out = (float*)d_out;
  char* ws = (char*)d_ws;

  u16*   t       = (u16*)(ws + 0);            // 25165824 ; reused as a_hat
  u16*   xm      = (u16*)(ws + 25165824);     // 25165824
  u16*   qh      = (u16*)(ws + 50331648);     // 33554432  [B,H,N,64]
  u16*   wpack   = (u16*)(ws + 83886080);     // 1179648
  u16*   pwb     = (u16*)(ws + 85065728);     // 294912
  u16*   wob     = (u16*)(ws + 85360640);     // 294912
  float* bpack   = (float*)(ws + 85655552);   // 6144
  float* kvacc   = (float*)(ws + 85661696);   // 589824  [64][48][48] f32
  float* ksumacc = (float*)(ws + 86251520);   // 12288   [64][48] f32
  u16*   kvp     = (u16*)(ws + 86263808);     // 524288  [64][64][64] bf16

  k0_prep<<<4044, 256, 0, stream>>>(wq,bq,wk,bk,wv,bv,wg,bg,pw_w,wo,
                                    wpack,pwb,wob,bpack,kvacc,ksumacc);
  k1_dw<<<3072, 256, 0, stream>>>(x, dw_w, dw_b, t);
  k2_gemm_pw<<<dim3(256,3), 256, 0, stream>>>(t, pwb, x, pw_b, xm);
  k3_gemm_qkvg<<<dim3(128,8), 1024, 0, stream>>>(xm, wpack, bpack, temp, qh, kvacc, ksumacc);
  k5_red<<<64, 256, 0, stream>>>(kvacc, ksumacc, kvp);
  k6_num<<<1024, 256, 0, stream>>>(qh, kvp, t /*a_hat*/);
  k7_gemm_out<<<dim3(256,3), 256, 0, stream>>>(t, wob, bo, out);
}

// Round 7
// 193.255 us; speedup vs baseline: 1.1922x; 1.1560x over previous
//
#include <hip/hip_runtime.h>
#include <math.h>

#define EPSF 1e-6f

typedef __attribute__((ext_vector_type(8))) short bf16x8;
typedef __attribute__((ext_vector_type(4))) float f32x4;
typedef unsigned short u16;
typedef unsigned int u32;

#define MFMA16(a,b,c) __builtin_amdgcn_mfma_f32_16x16x32_bf16((a),(b),(c),0,0,0)

__device__ __forceinline__ u16 f2bf(float f){
  u32 x = __builtin_bit_cast(u32, f);
  u32 r = (x + 0x7fffu + ((x >> 16) & 1u)) >> 16;
  return (u16)r;
}
__device__ __forceinline__ void gll16(const void* g, void* l){
  __builtin_amdgcn_global_load_lds(
      (const __attribute__((address_space(1))) u32*)g,
      (__attribute__((address_space(3))) u32*)l, 16, 0, 0);
}

// ---------------- k0: pack weights to bf16 + zero kv accumulators ---------
__global__ __launch_bounds__(256) void k0_prep(
    const float* __restrict__ wq, const float* __restrict__ bq,
    const float* __restrict__ wk, const float* __restrict__ bk,
    const float* __restrict__ wv, const float* __restrict__ bv,
    const float* __restrict__ wg, const float* __restrict__ bg,
    const float* __restrict__ pw_w, const float* __restrict__ wo,
    u16* __restrict__ wpack, u16* __restrict__ pwb, u16* __restrict__ wob,
    float* __restrict__ bpack, float* __restrict__ kvacc, float* __restrict__ ksumacc)
{
  int idx = blockIdx.x*256 + threadIdx.x;
  const int NW = 1536*384;
  if (idx < NW) {
    int r = idx / 384, c = idx - r*384;
    int h = r / 192, s = (r % 192)/48, d = r % 48;
    const float* w = (s==0)?wq:(s==1)?wk:(s==2)?wv:wg;
    wpack[idx] = f2bf(w[(h*48+d)*384 + c]);
    if (c==0){
      const float* b = (s==0)?bq:(s==1)?bk:(s==2)?bv:bg;
      bpack[r] = b[h*48+d];
    }
  } else if (idx < NW + 147456) {
    pwb[idx - NW] = f2bf(pw_w[idx - NW]);
  } else if (idx < NW + 2*147456) {
    wob[idx - NW - 147456] = f2bf(wo[idx - NW - 147456]);
  } else if (idx < NW + 2*147456 + 147456) {
    kvacc[idx - NW - 2*147456] = 0.f;
  } else if (idx < NW + 2*147456 + 147456 + 3072) {
    ksumacc[idx - NW - 2*147456 - 147456] = 0.f;
  }
}

// ---------------- k1: depthwise 3x3 conv (+dw_b) -> t bf16 ----------------
__global__ __launch_bounds__(256) void k1_dw(
    const float* __restrict__ x, const float* __restrict__ dw_w,
    const float* __restrict__ dw_b, u16* __restrict__ t)
{
  int idx = blockIdx.x*256 + threadIdx.x;   // 786432 threads
  int c4 = idx % 96; int rest = idx / 96;
  int jg = rest & 15; rest >>= 4;
  int i = rest & 63; int b = rest >> 6;
  int c0 = c4*4, j0 = jg*4;
  float wf[36];
  {
    const float4* wp = (const float4*)(dw_w + c0*9);
    #pragma unroll
    for (int k=0;k<9;k++){
      float4 v = wp[k];
      wf[4*k] = v.x; wf[4*k+1] = v.y; wf[4*k+2] = v.z; wf[4*k+3] = v.w;
    }
  }
  float4 bias = *(const float4*)(dw_b + c0);
  float acc[4][4];
  #pragma unroll
  for (int tk=0;tk<4;tk++){
    acc[tk][0]=bias.x; acc[tk][1]=bias.y; acc[tk][2]=bias.z; acc[tk][3]=bias.w;
  }
  const float* xb = x + ((size_t)b<<12)*384;
  #pragma unroll
  for (int di=-1; di<=1; ++di){
    int ii = i+di; if ((unsigned)ii >= 64u) continue;
    #pragma unroll
    for (int dj=-1; dj<=4; ++dj){
      int jj = j0+dj; if ((unsigned)jj >= 64u) continue;
      float4 xv = *(const float4*)(xb + (size_t)((ii<<6)+jj)*384 + c0);
      #pragma unroll
      for (int tk=0;tk<4;tk++){
        const int dd = dj - tk;
        if (dd < -1 || dd > 1) continue;
        const int tap = (di+1)*3 + (dd+1);
        acc[tk][0] = fmaf(xv.x, wf[0*9+tap], acc[tk][0]);
        acc[tk][1] = fmaf(xv.y, wf[1*9+tap], acc[tk][1]);
        acc[tk][2] = fmaf(xv.z, wf[2*9+tap], acc[tk][2]);
        acc[tk][3] = fmaf(xv.w, wf[3*9+tap], acc[tk][3]);
      }
    }
  }
  int mbase = (b<<12) + (i<<6) + j0;
  #pragma unroll
  for (int tk=0;tk<4;tk++){
    ushort4 o; o.x=f2bf(acc[tk][0]); o.y=f2bf(acc[tk][1]);
    o.z=f2bf(acc[tk][2]); o.w=f2bf(acc[tk][3]);
    *(ushort4*)(t + (size_t)(mbase+tk)*384 + c0) = o;
  }
}

// ---------------- k2: xm = bf16( x + t @ pw^T + pw_b ) --------------------
// R4 structure + chunk-XOR LDS swizzle (source-permuted within 128B window).
__global__ __launch_bounds__(256) void k2_gemm_pw(
    const u16* __restrict__ t, const u16* __restrict__ pwb,
    const float* __restrict__ x, const float* __restrict__ pw_b,
    u16* __restrict__ xm)
{
  __shared__ __align__(16) u16 As[128*64];
  __shared__ __align__(16) u16 Bs[128*64];
  const int m0 = blockIdx.x * 128;
  const int n0 = blockIdx.y * 128;
  const int tid = threadIdx.x, w = tid>>6, l = tid&63;
  const int lc = l & 15, hi = l >> 4;
  const int osw = ((l&7) ^ (l>>3))*16;   // swizzled chunk within row's 128B
  const f32x4 zf = {0.f,0.f,0.f,0.f};
  f32x4 acc[4][4];
  #pragma unroll
  for (int i=0;i<4;i++)
    #pragma unroll
    for (int j=0;j<4;j++) acc[i][j] = zf;

  for (int k0=0; k0<384; k0+=64) {
    #pragma unroll
    for (int i=0;i<4;i++){
      int ch = w*4+i;
      int row = ch*8 + (l>>3);
      gll16((const char*)t   + ((size_t)(m0+row)*384 + k0)*2 + osw, (char*)As + ch*1024);
      gll16((const char*)pwb + ((size_t)(n0+row)*384 + k0)*2 + osw, (char*)Bs + ch*1024);
    }
    __syncthreads();
    const int wr = (w>>1)*64, wc = (w&1)*64;
    #pragma unroll
    for (int kk=0; kk<64; kk+=32){
      const int sc = (((kk>>3)+hi) ^ (lc&7))*8;
      bf16x8 a[4], bb[4];
      #pragma unroll
      for (int i=0;i<4;i++) a[i]  = *(const bf16x8*)&As[(wr + i*16 + lc)*64 + sc];
      #pragma unroll
      for (int j=0;j<4;j++) bb[j] = *(const bf16x8*)&Bs[(wc + j*16 + lc)*64 + sc];
      #pragma unroll
      for (int i=0;i<4;i++)
        #pragma unroll
        for (int j=0;j<4;j++)
          acc[i][j] = MFMA16(a[i], bb[j], acc[i][j]);
    }
    __syncthreads();
  }
  const int wr=(w>>1)*64, wc=(w&1)*64;
  #pragma unroll
  for (int j=0;j<4;j++){
    int n = n0 + wc + j*16 + lc;
    float bias = pw_b[n];
    #pragma unroll
    for (int i=0;i<4;i++)
      #pragma unroll
      for (int r=0;r<4;r++){
        int m = m0 + wr + i*16 + hi*4 + r;
        float v = acc[i][j][r] + x[(size_t)m*384 + n] + bias;
        xm[(size_t)m*384 + n] = f2bf(v);
      }
  }
}

// ---------------- k3: fused QKVG GEMM + activations + kv/ksum accum -------
// R4 structure (grid 256x8, 4 waves, acc[2][12]) + chunk-XOR swizzle.
__global__ __launch_bounds__(256) void k3_gemm_qkvg(
    const u16* __restrict__ xm, const u16* __restrict__ wpack,
    const float* __restrict__ bpack, const float* __restrict__ temperature,
    u16* __restrict__ qh, float* __restrict__ kvacc, float* __restrict__ ksumacc)
{
  __shared__ __align__(16) u16 smem[20480];
  u16* As = smem;
  u16* Bs = smem + 8192;
  const int m0 = blockIdx.x * 128;
  const int h  = blockIdx.y;
  const int tid = threadIdx.x, w = tid>>6, l = tid&63;
  const int lc = l & 15, hi = l >> 4;
  const int osw = ((l&7) ^ (l>>3))*16;
  const f32x4 zf = {0.f,0.f,0.f,0.f};
  f32x4 acc[2][12];
  #pragma unroll
  for (int i=0;i<2;i++)
    #pragma unroll
    for (int j=0;j<12;j++) acc[i][j] = zf;

  for (int k0=0; k0<384; k0+=64){
    #pragma unroll
    for (int i=0;i<4;i++){
      int ch = w*4+i, row = ch*8 + (l>>3);
      gll16((const char*)xm + ((size_t)(m0+row)*384 + k0)*2 + osw, (char*)As + ch*1024);
    }
    #pragma unroll
    for (int i=0;i<6;i++){
      int ch = w*6+i, row = ch*8 + (l>>3);
      gll16((const char*)wpack + ((size_t)(h*192+row)*384 + k0)*2 + osw, (char*)Bs + ch*1024);
    }
    __syncthreads();
    const int rbase = w*32;
    #pragma unroll
    for (int kk=0; kk<64; kk+=32){
      const int sc = (((kk>>3)+hi) ^ (lc&7))*8;
      bf16x8 a0 = *(const bf16x8*)&As[(rbase +      lc)*64 + sc];
      bf16x8 a1 = *(const bf16x8*)&As[(rbase + 16 + lc)*64 + sc];
      #pragma unroll
      for (int j=0;j<12;j++){
        bf16x8 bb = *(const bf16x8*)&Bs[(j*16 + lc)*64 + sc];
        acc[0][j] = MFMA16(a0, bb, acc[0][j]);
        acc[1][j] = MFMA16(a1, bb, acc[1][j]);
      }
    }
    __syncthreads();
  }

  // ---- epilogue (R4 verbatim) ----
  const float tq = temperature[h];
  const int b = m0 >> 12;
  const size_t bh = (size_t)b*8 + h;
  const int bb0 = h*192;
  float biasq[3], biask[3], biasv[3], biasg[3];
  #pragma unroll
  for (int j=0;j<3;j++){
    biasq[j] = bpack[bb0       + j*16 + lc];
    biask[j] = bpack[bb0 + 48  + j*16 + lc];
    biasv[j] = bpack[bb0 + 96  + j*16 + lc];
    biasg[j] = bpack[bb0 + 144 + j*16 + lc];
  }
  u16* kT = smem;          // [48][136]
  u16* vT = smem + 6528;   // [48][136]
  float ksp[3] = {0.f, 0.f, 0.f};

  #pragma unroll
  for (int i=0;i<2;i++){
    ushort4 kst[3], vst[3];
    #pragma unroll
    for (int r=0;r<4;r++){
      int m = m0 + w*32 + i*16 + hi*4 + r;
      int n = m & 4095;
      size_t rowq = (bh*4096 + n)*64;
      float q0=(acc[i][0][r]+biasq[0])*tq;
      float q1=(acc[i][1][r]+biasq[1])*tq;
      float q2=(acc[i][2][r]+biasq[2])*tq;
      float mx = fmaxf(q0,fmaxf(q1,q2));
      mx = fmaxf(mx, __shfl_xor(mx,1,64));
      mx = fmaxf(mx, __shfl_xor(mx,2,64));
      mx = fmaxf(mx, __shfl_xor(mx,4,64));
      mx = fmaxf(mx, __shfl_xor(mx,8,64));
      qh[rowq +      lc] = f2bf(expf(q0-mx));
      qh[rowq + 16 + lc] = f2bf(expf(q1-mx));
      qh[rowq + 32 + lc] = f2bf(expf(q2-mx));
      qh[rowq + 48 + lc] = 0;
      float s0=acc[i][3][r]+biask[0];
      float s1=acc[i][4][r]+biask[1];
      float s2=acc[i][5][r]+biask[2];
      float mk = fmaxf(s0,fmaxf(s1,s2));
      mk = fmaxf(mk, __shfl_xor(mk,1,64));
      mk = fmaxf(mk, __shfl_xor(mk,2,64));
      mk = fmaxf(mk, __shfl_xor(mk,4,64));
      mk = fmaxf(mk, __shfl_xor(mk,8,64));
      float k0e = expf(s0-mk), k1e = expf(s1-mk), k2e = expf(s2-mk);
      ksp[0] += k0e; ksp[1] += k1e; ksp[2] += k2e;
      u16 kq0=f2bf(k0e), kq1=f2bf(k1e), kq2=f2bf(k2e);
      u16 vq[3];
      #pragma unroll
      for (int j=0;j<3;j++){
        float vv = acc[i][6+j][r] + biasv[j];
        float gg = acc[i][9+j][r] + biasg[j];
        float sg = 1.f/(1.f + expf(-gg));
        vq[j] = f2bf(vv*sg);
      }
      if (r==0){ kst[0].x=kq0; kst[1].x=kq1; kst[2].x=kq2; vst[0].x=vq[0]; vst[1].x=vq[1]; vst[2].x=vq[2]; }
      if (r==1){ kst[0].y=kq0; kst[1].y=kq1; kst[2].y=kq2; vst[0].y=vq[0]; vst[1].y=vq[1]; vst[2].y=vq[2]; }
      if (r==2){ kst[0].z=kq0; kst[1].z=kq1; kst[2].z=kq2; vst[0].z=vq[0]; vst[1].z=vq[1]; vst[2].z=vq[2]; }
      if (r==3){ kst[0].w=kq0; kst[1].w=kq1; kst[2].w=kq2; vst[0].w=vq[0]; vst[1].w=vq[1]; vst[2].w=vq[2]; }
    }
    int mb = w*32 + i*16 + hi*4;
    #pragma unroll
    for (int j=0;j<3;j++){
      *(ushort4*)&kT[(j*16+lc)*136 + mb] = kst[j];
      *(ushort4*)&vT[(j*16+lc)*136 + mb] = vst[j];
    }
  }
  __syncthreads();

  bf16x8 af[3], bfv[3];
  #pragma unroll
  for (int da=0;da<3;da++) af[da]  = *(const bf16x8*)&kT[(da*16+lc)*136 + w*32 + hi*8];
  #pragma unroll
  for (int eb=0;eb<3;eb++) bfv[eb] = *(const bf16x8*)&vT[(eb*16+lc)*136 + w*32 + hi*8];
  f32x4 a2[3][3];
  #pragma unroll
  for (int da=0;da<3;da++)
    #pragma unroll
    for (int eb=0;eb<3;eb++)
      a2[da][eb] = MFMA16(af[da], bfv[eb], zf);
  __syncthreads();
  float* pb = (float*)smem + w*2304;
  #pragma unroll
  for (int da=0;da<3;da++)
    #pragma unroll
    for (int eb=0;eb<3;eb++)
      #pragma unroll
      for (int rr=0;rr<4;rr++)
        pb[(da*16 + hi*4 + rr)*48 + eb*16 + lc] = a2[da][eb][rr];
  __syncthreads();
  float* p0 = (float*)smem;
  for (int u=tid; u<2304; u+=256){
    float s = p0[u] + p0[2304+u] + p0[4608+u] + p0[6912+u];
    atomicAdd(kvacc + bh*2304 + u, s);
  }
  #pragma unroll
  for (int j=0;j<3;j++){
    ksp[j] += __shfl_xor(ksp[j],16,64);
    ksp[j] += __shfl_xor(ksp[j],32,64);
  }
  if (hi==0){
    atomicAdd(ksumacc + bh*48 +      lc, ksp[0]);
    atomicAdd(ksumacc + bh*48 + 16 + lc, ksp[1]);
    atomicAdd(ksumacc + bh*48 + 32 + lc, ksp[2]);
  }
}

// ---------------- k5: kvacc/ksumacc -> kvp[e][d] bf16 (64x64, ksum row48) -
__global__ __launch_bounds__(256) void k5_red(
    const float* __restrict__ kvacc, const float* __restrict__ ksumacc,
    u16* __restrict__ kvp)
{
  int bh = blockIdx.x, tid = threadIdx.x;
  for (int u=tid; u<4096; u+=256){
    int e = u >> 6, d = u & 63;
    float v = 0.f;
    if (e < 48 && d < 48)       v = kvacc[(size_t)bh*2304 + d*48 + e];
    else if (e == 48 && d < 48) v = ksumacc[bh*48 + d];
    kvp[((size_t)bh*64 + e)*64 + d] = f2bf(v);
  }
}

// ---------------- k6: num/den -> a_hat bf16 [B,N,C] -----------------------
// R4 structure; staging via registers with the same chunk-XOR swizzle.
__global__ __launch_bounds__(256) void k6_num(
    const u16* __restrict__ qh, const u16* __restrict__ kvp, u16* __restrict__ ah)
{
  __shared__ __align__(16) u16 As[256*64]; // 32KB
  __shared__ __align__(16) u16 Bs[64*64];  // 8KB
  const int bh = blockIdx.x >> 4, nc = blockIdx.x & 15;
  const int tid = threadIdx.x, w = tid>>6, l = tid&63;
  const int lc = l & 15, hi = l >> 4;
  const f32x4 zf = {0.f,0.f,0.f,0.f};
  const u16* gq = qh + ((size_t)bh*4096 + nc*256)*64;
  #pragma unroll
  for (int it=0; it<8; ++it){
    int s = it*256 + tid;
    int row = s>>3, c = s&7, g = c ^ (row&7);
    ((uint4*)As)[s] = *(const uint4*)(gq + (size_t)row*64 + g*8);
  }
  const u16* gk = kvp + (size_t)bh*4096;
  #pragma unroll
  for (int it=0; it<2; ++it){
    int s = it*256 + tid;
    int row = s>>3, c = s&7, g = c ^ (row&7);
    ((uint4*)Bs)[s] = *(const uint4*)(gk + (size_t)row*64 + g*8);
  }
  __syncthreads();
  f32x4 acc[4][4];
  #pragma unroll
  for (int i=0;i<4;i++)
    #pragma unroll
    for (int j=0;j<4;j++) acc[i][j] = zf;
  const int rbase = w*64;
  #pragma unroll
  for (int kk=0; kk<64; kk+=32){
    const int sc = (((kk>>3)+hi) ^ (lc&7))*8;
    bf16x8 a[4], bb[4];
    #pragma unroll
    for (int i=0;i<4;i++) a[i]  = *(const bf16x8*)&As[(rbase + i*16 + lc)*64 + sc];
    #pragma unroll
    for (int j=0;j<4;j++) bb[j] = *(const bf16x8*)&Bs[(j*16 + lc)*64 + sc];
    #pragma unroll
    for (int i=0;i<4;i++)
      #pragma unroll
      for (int j=0;j<4;j++)
        acc[i][j] = MFMA16(a[i], bb[j], acc[i][j]);
  }
  const int b = bh >> 3, h = bh & 7;
  #pragma unroll
  for (int i=0;i<4;i++){
    #pragma unroll
    for (int r=0;r<4;r++){
      float den = __shfl(acc[i][3][r], l & 48, 64) + EPSF;
      float rd = 1.f/den;
      int n = nc*256 + rbase + i*16 + hi*4 + r;
      size_t ob = ((size_t)b*4096 + n)*384 + h*48;
      ah[ob +      lc] = f2bf(acc[i][0][r]*rd);
      ah[ob + 16 + lc] = f2bf(acc[i][1][r]*rd);
      ah[ob + 32 + lc] = f2bf(acc[i][2][r]*rd);
    }
  }
}

// ---------------- k7: out = a_hat @ wo^T + bo (fp32) ----------------------
__global__ __launch_bounds__(256) void k7_gemm_out(
    const u16* __restrict__ ah, const u16* __restrict__ wob,
    const float* __restrict__ bo, float* __restrict__ out)
{
  __shared__ __align__(16) u16 As[128*64];
  __shared__ __align__(16) u16 Bs[128*64];
  const int m0 = blockIdx.x * 128;
  const int n0 = blockIdx.y * 128;
  const int tid = threadIdx.x, w = tid>>6, l = tid&63;
  const int lc = l & 15, hi = l >> 4;
  const int osw = ((l&7) ^ (l>>3))*16;
  const f32x4 zf = {0.f,0.f,0.f,0.f};
  f32x4 acc[4][4];
  #pragma unroll
  for (int i=0;i<4;i++)
    #pragma unroll
    for (int j=0;j<4;j++) acc[i][j] = zf;

  for (int k0=0; k0<384; k0+=64) {
    #pragma unroll
    for (int i=0;i<4;i++){
      int ch = w*4+i;
      int row = ch*8 + (l>>3);
      gll16((const char*)ah  + ((size_t)(m0+row)*384 + k0)*2 + osw, (char*)As + ch*1024);
      gll16((const char*)wob + ((size_t)(n0+row)*384 + k0)*2 + osw, (char*)Bs + ch*1024);
    }
    __syncthreads();
    const int wr = (w>>1)*64, wc = (w&1)*64;
    #pragma unroll
    for (int kk=0; kk<64; kk+=32){
      const int sc = (((kk>>3)+hi) ^ (lc&7))*8;
      bf16x8 a[4], bb[4];
      #pragma unroll
      for (int i=0;i<4;i++) a[i]  = *(const bf16x8*)&As[(wr + i*16 + lc)*64 + sc];
      #pragma unroll
      for (int j=0;j<4;j++) bb[j] = *(const bf16x8*)&Bs[(wc + j*16 + lc)*64 + sc];
      #pragma unroll
      for (int i=0;i<4;i++)
        #pragma unroll
        for (int j=0;j<4;j++)
          acc[i][j] = MFMA16(a[i], bb[j], acc[i][j]);
    }
    __syncthreads();
  }
  const int wr=(w>>1)*64, wc=(w&1)*64;
  #pragma unroll
  for (int j=0;j<4;j++){
    int n = n0 + wc + j*16 + lc;
    float bias = bo[n];
    #pragma unroll
    for (int i=0;i<4;i++)
      #pragma unroll
      for (int r=0;r<4;r++){
        int m = m0 + wr + i*16 + hi*4 + r;
        out[(size_t)m*384 + n] = acc[i][j][r] + bias;
      }
  }
}

extern "C" void kernel_launch(void* const* d_in, const int* in_sizes, int n_in,
                              void* d_out, int out_size, void* d_ws, size_t ws_size,
                              hipStream_t stream)
{
  const float* x    = (const float*)d_in[0];
  const float* wq   = (const float*)d_in[1];
  const float* bq   = (const float*)d_in[2];
  const float* wk   = (const float*)d_in[3];
  const float* bk   = (const float*)d_in[4];
  const float* wv   = (const float*)d_in[5];
  const float* bv   = (const float*)d_in[6];
  const float* wg   = (const float*)d_in[7];
  const float* bg   = (const float*)d_in[8];
  const float* wo   = (const float*)d_in[9];
  const float* bo   = (const float*)d_in[10];
  const float* temp = (const float*)d_in[11];
  const float* dw_w = (const float*)d_in[12];
  const float* dw_b = (const float*)d_in[13];
  const float* pw_w = (const float*)d_in[14];
  const float* pw_b = (const float*)d_in[15];
  float* out = (float*)d_out;
  char* ws = (char*)d_ws;

  u16*   t       = (u16*)(ws + 0);            // 25165824 ; reused as a_hat
  u16*   xm      = (u16*)(ws + 25165824);     // 25165824
  u16*   qh      = (u16*)(ws + 50331648);     // 33554432  [B,H,N,64]
  u16*   wpack   = (u16*)(ws + 83886080);     // 1179648
  u16*   pwb     = (u16*)(ws + 85065728);     // 294912
  u16*   wob     = (u16*)(ws + 85360640);     // 294912
  float* bpack   = (float*)(ws + 85655552);   // 6144
  float* kvacc   = (float*)(ws + 85661696);   // 589824  [64][48][48] f32
  float* ksumacc = (float*)(ws + 86251520);   // 12288   [64][48] f32
  u16*   kvp     = (u16*)(ws + 86263808);     // 524288  [64][64][64] bf16

  k0_prep<<<4044, 256, 0, stream>>>(wq,bq,wk,bk,wv,bv,wg,bg,pw_w,wo,
                                    wpack,pwb,wob,bpack,kvacc,ksumacc);
  k1_dw<<<3072, 256, 0, stream>>>(x, dw_w, dw_b, t);
  k2_gemm_pw<<<dim3(256,3), 256, 0, stream>>>(t, pwb, x, pw_b, xm);
  k3_gemm_qkvg<<<dim3(256,8), 256, 0, stream>>>(xm, wpack, bpack, temp, qh, kvacc, ksumacc);
  k5_red<<<64, 256, 0, stream>>>(kvacc, ksumacc, kvp);
  k6_num<<<1024, 256, 0, stream>>>(qh, kvp, t /*a_hat*/);
  k7_gemm_out<<<dim3(256,3), 256, 0, stream>>>(t, wob, bo, out);
}

// Round 8
// 190.930 us; speedup vs baseline: 1.2067x; 1.0122x over previous
//
#include <hip/hip_runtime.h>
#include <math.h>

#define EPSF 1e-6f

typedef __attribute__((ext_vector_type(8))) short bf16x8;
typedef __attribute__((ext_vector_type(4))) float f32x4;
typedef unsigned short u16;
typedef unsigned int u32;

#define MFMA16(a,b,c) __builtin_amdgcn_mfma_f32_16x16x32_bf16((a),(b),(c),0,0,0)

__device__ __forceinline__ u16 f2bf(float f){
  u32 x = __builtin_bit_cast(u32, f);
  u32 r = (x + 0x7fffu + ((x >> 16) & 1u)) >> 16;
  return (u16)r;
}
__device__ __forceinline__ void gll16(const void* g, void* l){
  __builtin_amdgcn_global_load_lds(
      (const __attribute__((address_space(1))) u32*)g,
      (__attribute__((address_space(3))) u32*)l, 16, 0, 0);
}

// ---------------- k0: pack weights to bf16 + zero kv accumulators ---------
__global__ __launch_bounds__(256) void k0_prep(
    const float* __restrict__ wq, const float* __restrict__ bq,
    const float* __restrict__ wk, const float* __restrict__ bk,
    const float* __restrict__ wv, const float* __restrict__ bv,
    const float* __restrict__ wg, const float* __restrict__ bg,
    const float* __restrict__ pw_w, const float* __restrict__ wo,
    u16* __restrict__ wpack, u16* __restrict__ pwb, u16* __restrict__ wob,
    float* __restrict__ bpack, float* __restrict__ kvacc, float* __restrict__ ksumacc)
{
  int idx = blockIdx.x*256 + threadIdx.x;
  const int NW = 1536*384;
  if (idx < NW) {
    int r = idx / 384, c = idx - r*384;
    int h = r / 192, s = (r % 192)/48, d = r % 48;
    const float* w = (s==0)?wq:(s==1)?wk:(s==2)?wv:wg;
    wpack[idx] = f2bf(w[(h*48+d)*384 + c]);
    if (c==0){
      const float* b = (s==0)?bq:(s==1)?bk:(s==2)?bv:bg;
      bpack[r] = b[h*48+d];
    }
  } else if (idx < NW + 147456) {
    pwb[idx - NW] = f2bf(pw_w[idx - NW]);
  } else if (idx < NW + 2*147456) {
    wob[idx - NW - 147456] = f2bf(wo[idx - NW - 147456]);
  } else if (idx < NW + 2*147456 + 147456) {
    kvacc[idx - NW - 2*147456] = 0.f;
  } else if (idx < NW + 2*147456 + 147456 + 3072) {
    ksumacc[idx - NW - 2*147456 - 147456] = 0.f;
  }
}

// ---------------- k1: depthwise 3x3 conv (+dw_b) -> t bf16 ----------------
__global__ __launch_bounds__(256) void k1_dw(
    const float* __restrict__ x, const float* __restrict__ dw_w,
    const float* __restrict__ dw_b, u16* __restrict__ t)
{
  int idx = blockIdx.x*256 + threadIdx.x;   // 786432 threads
  int c4 = idx % 96; int rest = idx / 96;
  int jg = rest & 15; rest >>= 4;
  int i = rest & 63; int b = rest >> 6;
  int c0 = c4*4, j0 = jg*4;
  float wf[36];
  {
    const float4* wp = (const float4*)(dw_w + c0*9);
    #pragma unroll
    for (int k=0;k<9;k++){
      float4 v = wp[k];
      wf[4*k] = v.x; wf[4*k+1] = v.y; wf[4*k+2] = v.z; wf[4*k+3] = v.w;
    }
  }
  float4 bias = *(const float4*)(dw_b + c0);
  float acc[4][4];
  #pragma unroll
  for (int tk=0;tk<4;tk++){
    acc[tk][0]=bias.x; acc[tk][1]=bias.y; acc[tk][2]=bias.z; acc[tk][3]=bias.w;
  }
  const float* xb = x + ((size_t)b<<12)*384;
  #pragma unroll
  for (int di=-1; di<=1; ++di){
    int ii = i+di; if ((unsigned)ii >= 64u) continue;
    #pragma unroll
    for (int dj=-1; dj<=4; ++dj){
      int jj = j0+dj; if ((unsigned)jj >= 64u) continue;
      float4 xv = *(const float4*)(xb + (size_t)((ii<<6)+jj)*384 + c0);
      #pragma unroll
      for (int tk=0;tk<4;tk++){
        const int dd = dj - tk;
        if (dd < -1 || dd > 1) continue;
        const int tap = (di+1)*3 + (dd+1);
        acc[tk][0] = fmaf(xv.x, wf[0*9+tap], acc[tk][0]);
        acc[tk][1] = fmaf(xv.y, wf[1*9+tap], acc[tk][1]);
        acc[tk][2] = fmaf(xv.z, wf[2*9+tap], acc[tk][2]);
        acc[tk][3] = fmaf(xv.w, wf[3*9+tap], acc[tk][3]);
      }
    }
  }
  int mbase = (b<<12) + (i<<6) + j0;
  #pragma unroll
  for (int tk=0;tk<4;tk++){
    ushort4 o; o.x=f2bf(acc[tk][0]); o.y=f2bf(acc[tk][1]);
    o.z=f2bf(acc[tk][2]); o.w=f2bf(acc[tk][3]);
    *(ushort4*)(t + (size_t)(mbase+tk)*384 + c0) = o;
  }
}

// ---------------- k2: xm = bf16( x + t @ pw^T + pw_b ) --------------------
__global__ __launch_bounds__(256) void k2_gemm_pw(
    const u16* __restrict__ t, const u16* __restrict__ pwb,
    const float* __restrict__ x, const float* __restrict__ pw_b,
    u16* __restrict__ xm)
{
  __shared__ __align__(16) u16 As[128*64];
  __shared__ __align__(16) u16 Bs[128*64];
  const int m0 = blockIdx.x * 128;
  const int n0 = blockIdx.y * 128;
  const int tid = threadIdx.x, w = tid>>6, l = tid&63;
  const int lc = l & 15, hi = l >> 4;
  const int osw = ((l&7) ^ (l>>3))*16;   // swizzled chunk within row's 128B
  const f32x4 zf = {0.f,0.f,0.f,0.f};
  f32x4 acc[4][4];
  #pragma unroll
  for (int i=0;i<4;i++)
    #pragma unroll
    for (int j=0;j<4;j++) acc[i][j] = zf;

  for (int k0=0; k0<384; k0+=64) {
    #pragma unroll
    for (int i=0;i<4;i++){
      int ch = w*4+i;
      int row = ch*8 + (l>>3);
      gll16((const char*)t   + ((size_t)(m0+row)*384 + k0)*2 + osw, (char*)As + ch*1024);
      gll16((const char*)pwb + ((size_t)(n0+row)*384 + k0)*2 + osw, (char*)Bs + ch*1024);
    }
    __syncthreads();
    const int wr = (w>>1)*64, wc = (w&1)*64;
    #pragma unroll
    for (int kk=0; kk<64; kk+=32){
      const int sc = (((kk>>3)+hi) ^ (lc&7))*8;
      bf16x8 a[4], bb[4];
      #pragma unroll
      for (int i=0;i<4;i++) a[i]  = *(const bf16x8*)&As[(wr + i*16 + lc)*64 + sc];
      #pragma unroll
      for (int j=0;j<4;j++) bb[j] = *(const bf16x8*)&Bs[(wc + j*16 + lc)*64 + sc];
      #pragma unroll
      for (int i=0;i<4;i++)
        #pragma unroll
        for (int j=0;j<4;j++)
          acc[i][j] = MFMA16(a[i], bb[j], acc[i][j]);
    }
    __syncthreads();
  }
  const int wr=(w>>1)*64, wc=(w&1)*64;
  #pragma unroll
  for (int j=0;j<4;j++){
    int n = n0 + wc + j*16 + lc;
    float bias = pw_b[n];
    #pragma unroll
    for (int i=0;i<4;i++)
      #pragma unroll
      for (int r=0;r<4;r++){
        int m = m0 + wr + i*16 + hi*4 + r;
        float v = acc[i][j][r] + x[(size_t)m*384 + n] + bias;
        xm[(size_t)m*384 + n] = f2bf(v);
      }
  }
}

// ---------------- k3: fused QKVG GEMM + activations + kv/ksum accum -------
// R7 structure + double-buffered prefetch (stage t+1 before compute t).
// LDS 80KB: As dbuf 2x16KB (u16 off 0/8192), Bs dbuf 2x24KB (16384/28672).
__global__ __launch_bounds__(256) void k3_gemm_qkvg(
    const u16* __restrict__ xm, const u16* __restrict__ wpack,
    const float* __restrict__ bpack, const float* __restrict__ temperature,
    u16* __restrict__ qh, float* __restrict__ kvacc, float* __restrict__ ksumacc)
{
  __shared__ __align__(16) u16 smem[40960];   // 80KB
  const int m0 = blockIdx.x * 128;
  const int h  = blockIdx.y;
  const int tid = threadIdx.x, w = tid>>6, l = tid&63;
  const int lc = l & 15, hi = l >> 4;
  const int osw = ((l&7) ^ (l>>3))*16;
  const f32x4 zf = {0.f,0.f,0.f,0.f};
  f32x4 acc[2][12];
  #pragma unroll
  for (int i=0;i<2;i++)
    #pragma unroll
    for (int j=0;j<12;j++) acc[i][j] = zf;

  const int arow = (w*4)*8 + (l>>3);          // A: chunk = w*4+i
  const int brow = (w*6)*8 + (l>>3);          // B: chunk = w*6+i

  #define K3_STAGE(T, BUF) do {                                                \
    const int k0_ = (T)*64;                                                    \
    char* Ab_ = (char*)(smem + (BUF)*8192);                                    \
    char* Bb_ = (char*)(smem + 16384 + (BUF)*12288);                           \
    _Pragma("unroll")                                                          \
    for (int i=0;i<4;i++)                                                      \
      gll16((const char*)xm + ((size_t)(m0+arow+i*8)*384 + k0_)*2 + osw,       \
            Ab_ + (w*4+i)*1024);                                               \
    _Pragma("unroll")                                                          \
    for (int i=0;i<6;i++)                                                      \
      gll16((const char*)wpack + ((size_t)(h*192+brow+i*8)*384 + k0_)*2 + osw, \
            Bb_ + (w*6+i)*1024);                                               \
  } while(0)

  K3_STAGE(0, 0);
  __syncthreads();
  int cur = 0;
  const int rbase = w*32;
  for (int t=0; t<6; ++t){
    if (t < 5) K3_STAGE(t+1, cur^1);
    const u16* Ab = smem + cur*8192;
    const u16* Bb = smem + 16384 + cur*12288;
    #pragma unroll
    for (int kk=0; kk<64; kk+=32){
      const int sc = (((kk>>3)+hi) ^ (lc&7))*8;
      bf16x8 a0 = *(const bf16x8*)&Ab[(rbase +      lc)*64 + sc];
      bf16x8 a1 = *(const bf16x8*)&Ab[(rbase + 16 + lc)*64 + sc];
      #pragma unroll
      for (int j=0;j<12;j++){
        bf16x8 bb = *(const bf16x8*)&Bb[(j*16 + lc)*64 + sc];
        acc[0][j] = MFMA16(a0, bb, acc[0][j]);
        acc[1][j] = MFMA16(a1, bb, acc[1][j]);
      }
    }
    __syncthreads();
    cur ^= 1;
  }
  #undef K3_STAGE

  // ---- epilogue (R7 verbatim; LDS reused after final barrier) ----
  const float tq = temperature[h];
  const int b = m0 >> 12;
  const size_t bh = (size_t)b*8 + h;
  const int bb0 = h*192;
  float biasq[3], biask[3], biasv[3], biasg[3];
  #pragma unroll
  for (int j=0;j<3;j++){
    biasq[j] = bpack[bb0       + j*16 + lc];
    biask[j] = bpack[bb0 + 48  + j*16 + lc];
    biasv[j] = bpack[bb0 + 96  + j*16 + lc];
    biasg[j] = bpack[bb0 + 144 + j*16 + lc];
  }
  u16* kT = smem;          // [48][136]
  u16* vT = smem + 6528;   // [48][136]
  float ksp[3] = {0.f, 0.f, 0.f};

  #pragma unroll
  for (int i=0;i<2;i++){
    ushort4 kst[3], vst[3];
    #pragma unroll
    for (int r=0;r<4;r++){
      int m = m0 + w*32 + i*16 + hi*4 + r;
      int n = m & 4095;
      size_t rowq = (bh*4096 + n)*64;
      float q0=(acc[i][0][r]+biasq[0])*tq;
      float q1=(acc[i][1][r]+biasq[1])*tq;
      float q2=(acc[i][2][r]+biasq[2])*tq;
      float mx = fmaxf(q0,fmaxf(q1,q2));
      mx = fmaxf(mx, __shfl_xor(mx,1,64));
      mx = fmaxf(mx, __shfl_xor(mx,2,64));
      mx = fmaxf(mx, __shfl_xor(mx,4,64));
      mx = fmaxf(mx, __shfl_xor(mx,8,64));
      qh[rowq +      lc] = f2bf(expf(q0-mx));
      qh[rowq + 16 + lc] = f2bf(expf(q1-mx));
      qh[rowq + 32 + lc] = f2bf(expf(q2-mx));
      qh[rowq + 48 + lc] = 0;
      float s0=acc[i][3][r]+biask[0];
      float s1=acc[i][4][r]+biask[1];
      float s2=acc[i][5][r]+biask[2];
      float mk = fmaxf(s0,fmaxf(s1,s2));
      mk = fmaxf(mk, __shfl_xor(mk,1,64));
      mk = fmaxf(mk, __shfl_xor(mk,2,64));
      mk = fmaxf(mk, __shfl_xor(mk,4,64));
      mk = fmaxf(mk, __shfl_xor(mk,8,64));
      float k0e = expf(s0-mk), k1e = expf(s1-mk), k2e = expf(s2-mk);
      ksp[0] += k0e; ksp[1] += k1e; ksp[2] += k2e;
      u16 kq0=f2bf(k0e), kq1=f2bf(k1e), kq2=f2bf(k2e);
      u16 vq[3];
      #pragma unroll
      for (int j=0;j<3;j++){
        float vv = acc[i][6+j][r] + biasv[j];
        float gg = acc[i][9+j][r] + biasg[j];
        float sg = 1.f/(1.f + expf(-gg));
        vq[j] = f2bf(vv*sg);
      }
      if (r==0){ kst[0].x=kq0; kst[1].x=kq1; kst[2].x=kq2; vst[0].x=vq[0]; vst[1].x=vq[1]; vst[2].x=vq[2]; }
      if (r==1){ kst[0].y=kq0; kst[1].y=kq1; kst[2].y=kq2; vst[0].y=vq[0]; vst[1].y=vq[1]; vst[2].y=vq[2]; }
      if (r==2){ kst[0].z=kq0; kst[1].z=kq1; kst[2].z=kq2; vst[0].z=vq[0]; vst[1].z=vq[1]; vst[2].z=vq[2]; }
      if (r==3){ kst[0].w=kq0; kst[1].w=kq1; kst[2].w=kq2; vst[0].w=vq[0]; vst[1].w=vq[1]; vst[2].w=vq[2]; }
    }
    int mb = w*32 + i*16 + hi*4;
    #pragma unroll
    for (int j=0;j<3;j++){
      *(ushort4*)&kT[(j*16+lc)*136 + mb] = kst[j];
      *(ushort4*)&vT[(j*16+lc)*136 + mb] = vst[j];
    }
  }
  __syncthreads();

  bf16x8 af[3], bfv[3];
  #pragma unroll
  for (int da=0;da<3;da++) af[da]  = *(const bf16x8*)&kT[(da*16+lc)*136 + w*32 + hi*8];
  #pragma unroll
  for (int eb=0;eb<3;eb++) bfv[eb] = *(const bf16x8*)&vT[(eb*16+lc)*136 + w*32 + hi*8];
  f32x4 a2[3][3];
  #pragma unroll
  for (int da=0;da<3;da++)
    #pragma unroll
    for (int eb=0;eb<3;eb++)
      a2[da][eb] = MFMA16(af[da], bfv[eb], zf);
  __syncthreads();
  float* pb = (float*)smem + w*2304;
  #pragma unroll
  for (int da=0;da<3;da++)
    #pragma unroll
    for (int eb=0;eb<3;eb++)
      #pragma unroll
      for (int rr=0;rr<4;rr++)
        pb[(da*16 + hi*4 + rr)*48 + eb*16 + lc] = a2[da][eb][rr];
  __syncthreads();
  float* p0 = (float*)smem;
  for (int u=tid; u<2304; u+=256){
    float s = p0[u] + p0[2304+u] + p0[4608+u] + p0[6912+u];
    atomicAdd(kvacc + bh*2304 + u, s);
  }
  #pragma unroll
  for (int j=0;j<3;j++){
    ksp[j] += __shfl_xor(ksp[j],16,64);
    ksp[j] += __shfl_xor(ksp[j],32,64);
  }
  if (hi==0){
    atomicAdd(ksumacc + bh*48 +      lc, ksp[0]);
    atomicAdd(ksumacc + bh*48 + 16 + lc, ksp[1]);
    atomicAdd(ksumacc + bh*48 + 32 + lc, ksp[2]);
  }
}

// ---------------- k5: kvacc/ksumacc -> kvp[e][d] bf16 (64x64, ksum row48) -
__global__ __launch_bounds__(256) void k5_red(
    const float* __restrict__ kvacc, const float* __restrict__ ksumacc,
    u16* __restrict__ kvp)
{
  int bh = blockIdx.x, tid = threadIdx.x;
  for (int u=tid; u<4096; u+=256){
    int e = u >> 6, d = u & 63;
    float v = 0.f;
    if (e < 48 && d < 48)       v = kvacc[(size_t)bh*2304 + d*48 + e];
    else if (e == 48 && d < 48) v = ksumacc[bh*48 + d];
    kvp[((size_t)bh*64 + e)*64 + d] = f2bf(v);
  }
}

// ---------------- k6: num/den -> a_hat bf16 [B,N,C] -----------------------
__global__ __launch_bounds__(256) void k6_num(
    const u16* __restrict__ qh, const u16* __restrict__ kvp, u16* __restrict__ ah)
{
  __shared__ __align__(16) u16 As[256*64]; // 32KB
  __shared__ __align__(16) u16 Bs[64*64];  // 8KB
  const int bh = blockIdx.x >> 4, nc = blockIdx.x & 15;
  const int tid = threadIdx.x, w = tid>>6, l = tid&63;
  const int lc = l & 15, hi = l >> 4;
  const f32x4 zf = {0.f,0.f,0.f,0.f};
  const u16* gq = qh + ((size_t)bh*4096 + nc*256)*64;
  #pragma unroll
  for (int it=0; it<8; ++it){
    int s = it*256 + tid;
    int row = s>>3, c = s&7, g = c ^ (row&7);
    ((uint4*)As)[s] = *(const uint4*)(gq + (size_t)row*64 + g*8);
  }
  const u16* gk = kvp + (size_t)bh*4096;
  #pragma unroll
  for (int it=0; it<2; ++it){
    int s = it*256 + tid;
    int row = s>>3, c = s&7, g = c ^ (row&7);
    ((uint4*)Bs)[s] = *(const uint4*)(gk + (size_t)row*64 + g*8);
  }
  __syncthreads();
  f32x4 acc[4][4];
  #pragma unroll
  for (int i=0;i<4;i++)
    #pragma unroll
    for (int j=0;j<4;j++) acc[i][j] = zf;
  const int rbase = w*64;
  #pragma unroll
  for (int kk=0; kk<64; kk+=32){
    const int sc = (((kk>>3)+hi) ^ (lc&7))*8;
    bf16x8 a[4], bb[4];
    #pragma unroll
    for (int i=0;i<4;i++) a[i]  = *(const bf16x8*)&As[(rbase + i*16 + lc)*64 + sc];
    #pragma unroll
    for (int j=0;j<4;j++) bb[j] = *(const bf16x8*)&Bs[(j*16 + lc)*64 + sc];
    #pragma unroll
    for (int i=0;i<4;i++)
      #pragma unroll
      for (int j=0;j<4;j++)
        acc[i][j] = MFMA16(a[i], bb[j], acc[i][j]);
  }
  const int b = bh >> 3, h = bh & 7;
  #pragma unroll
  for (int i=0;i<4;i++){
    #pragma unroll
    for (int r=0;r<4;r++){
      float den = __shfl(acc[i][3][r], l & 48, 64) + EPSF;
      float rd = 1.f/den;
      int n = nc*256 + rbase + i*16 + hi*4 + r;
      size_t ob = ((size_t)b*4096 + n)*384 + h*48;
      ah[ob +      lc] = f2bf(acc[i][0][r]*rd);
      ah[ob + 16 + lc] = f2bf(acc[i][1][r]*rd);
      ah[ob + 32 + lc] = f2bf(acc[i][2][r]*rd);
    }
  }
}

// ---------------- k7: out = a_hat @ wo^T + bo (fp32) ----------------------
__global__ __launch_bounds__(256) void k7_gemm_out(
    const u16* __restrict__ ah, const u16* __restrict__ wob,
    const float* __restrict__ bo, float* __restrict__ out)
{
  __shared__ __align__(16) u16 As[128*64];
  __shared__ __align__(16) u16 Bs[128*64];
  const int m0 = blockIdx.x * 128;
  const int n0 = blockIdx.y * 128;
  const int tid = threadIdx.x, w = tid>>6, l = tid&63;
  const int lc = l & 15, hi = l >> 4;
  const int osw = ((l&7) ^ (l>>3))*16;
  const f32x4 zf = {0.f,0.f,0.f,0.f};
  f32x4 acc[4][4];
  #pragma unroll
  for (int i=0;i<4;i++)
    #pragma unroll
    for (int j=0;j<4;j++) acc[i][j] = zf;

  for (int k0=0; k0<384; k0+=64) {
    #pragma unroll
    for (int i=0;i<4;i++){
      int ch = w*4+i;
      int row = ch*8 + (l>>3);
      gll16((const char*)ah  + ((size_t)(m0+row)*384 + k0)*2 + osw, (char*)As + ch*1024);
      gll16((const char*)wob + ((size_t)(n0+row)*384 + k0)*2 + osw, (char*)Bs + ch*1024);
    }
    __syncthreads();
    const int wr = (w>>1)*64, wc = (w&1)*64;
    #pragma unroll
    for (int kk=0; kk<64; kk+=32){
      const int sc = (((kk>>3)+hi) ^ (lc&7))*8;
      bf16x8 a[4], bb[4];
      #pragma unroll
      for (int i=0;i<4;i++) a[i]  = *(const bf16x8*)&As[(wr + i*16 + lc)*64 + sc];
      #pragma unroll
      for (int j=0;j<4;j++) bb[j] = *(const bf16x8*)&Bs[(wc + j*16 + lc)*64 + sc];
      #pragma unroll
      for (int i=0;i<4;i++)
        #pragma unroll
        for (int j=0;j<4;j++)
          acc[i][j] = MFMA16(a[i], bb[j], acc[i][j]);
    }
    __syncthreads();
  }
  const int wr=(w>>1)*64, wc=(w&1)*64;
  #pragma unroll
  for (int j=0;j<4;j++){
    int n = n0 + wc + j*16 + lc;
    float bias = bo[n];
    #pragma unroll
    for (int i=0;i<4;i++)
      #pragma unroll
      for (int r=0;r<4;r++){
        int m = m0 + wr + i*16 + hi*4 + r;
        out[(size_t)m*384 + n] = acc[i][j][r] + bias;
      }
  }
}

extern "C" void kernel_launch(void* const* d_in, const int* in_sizes, int n_in,
                              void* d_out, int out_size, void* d_ws, size_t ws_size,
                              hipStream_t stream)
{
  const float* x    = (const float*)d_in[0];
  const float* wq   = (const float*)d_in[1];
  const float* bq   = (const float*)d_in[2];
  const float* wk   = (const float*)d_in[3];
  const float* bk   = (const float*)d_in[4];
  const float* wv   = (const float*)d_in[5];
  const float* bv   = (const float*)d_in[6];
  const float* wg   = (const float*)d_in[7];
  const float* bg   = (const float*)d_in[8];
  const float* wo   = (const float*)d_in[9];
  const float* bo   = (const float*)d_in[10];
  const float* temp = (const float*)d_in[11];
  const float* dw_w = (const float*)d_in[12];
  const float* dw_b = (const float*)d_in[13];
  const float* pw_w = (const float*)d_in[14];
  const float* pw_b = (const float*)d_in[15];
  float* out = (float*)d_out;
  char* ws = (char*)d_ws;

  u16*   t       = (u16*)(ws + 0);            // 25165824 ; reused as a_hat
  u16*   xm      = (u16*)(ws + 25165824);     // 25165824
  u16*   qh      = (u16*)(ws + 50331648);     // 33554432  [B,H,N,64]
  u16*   wpack   = (u16*)(ws + 83886080);     // 1179648
  u16*   pwb     = (u16*)(ws + 85065728);     // 294912
  u16*   wob     = (u16*)(ws + 85360640);     // 294912
  float* bpack   = (float*)(ws + 85655552);   // 6144
  float* kvacc   = (float*)(ws + 85661696);   // 589824  [64][48][48] f32
  float* ksumacc = (float*)(ws + 86251520);   // 12288   [64][48] f32
  u16*   kvp     = (u16*)(ws + 86263808);     // 524288  [64][64][64] bf16

  k0_prep<<<4044, 256, 0, stream>>>(wq,bq,wk,bk,wv,bv,wg,bg,pw_w,wo,
                                    wpack,pwb,wob,bpack,kvacc,ksumacc);
  k1_dw<<<3072, 256, 0, stream>>>(x, dw_w, dw_b, t);
  k2_gemm_pw<<<dim3(256,3), 256, 0, stream>>>(t, pwb, x, pw_b, xm);
  k3_gemm_qkvg<<<dim3(256,8), 256, 0, stream>>>(xm, wpack, bpack, temp, qh, kvacc, ksumacc);
  k5_red<<<64, 256, 0, stream>>>(kvacc, ksumacc, kvp);
  k6_num<<<1024, 256, 0, stream>>>(qh, kvp, t /*a_hat*/);
  k7_gemm_out<<<dim3(256,3), 256, 0, stream>>>(t, wob, bo, out);
}

// Round 9
// 186.600 us; speedup vs baseline: 1.2347x; 1.0232x over previous
//
#include <hip/hip_runtime.h>
#include <math.h>

#define EPSF 1e-6f

typedef __attribute__((ext_vector_type(8))) short bf16x8;
typedef __attribute__((ext_vector_type(4))) float f32x4;
typedef unsigned short u16;
typedef unsigned int u32;

#define MFMA16(a,b,c) __builtin_amdgcn_mfma_f32_16x16x32_bf16((a),(b),(c),0,0,0)

__device__ __forceinline__ u16 f2bf(float f){
  u32 x = __builtin_bit_cast(u32, f);
  u32 r = (x + 0x7fffu + ((x >> 16) & 1u)) >> 16;
  return (u16)r;
}
__device__ __forceinline__ void gll16(const void* g, void* l){
  __builtin_amdgcn_global_load_lds(
      (const __attribute__((address_space(1))) u32*)g,
      (__attribute__((address_space(3))) u32*)l, 16, 0, 0);
}

// ---------------- k0: pack weights to bf16 ---------------------------------
__global__ __launch_bounds__(256) void k0_prep(
    const float* __restrict__ wq, const float* __restrict__ bq,
    const float* __restrict__ wk, const float* __restrict__ bk,
    const float* __restrict__ wv, const float* __restrict__ bv,
    const float* __restrict__ wg, const float* __restrict__ bg,
    const float* __restrict__ pw_w, const float* __restrict__ wo,
    u16* __restrict__ wpack, u16* __restrict__ pwb, u16* __restrict__ wob,
    float* __restrict__ bpack)
{
  int idx = blockIdx.x*256 + threadIdx.x;
  const int NW = 1536*384;
  if (idx < NW) {
    int r = idx / 384, c = idx - r*384;
    int h = r / 192, s = (r % 192)/48, d = r % 48;
    const float* w = (s==0)?wq:(s==1)?wk:(s==2)?wv:wg;
    wpack[idx] = f2bf(w[(h*48+d)*384 + c]);
    if (c==0){
      const float* b = (s==0)?bq:(s==1)?bk:(s==2)?bv:bg;
      bpack[r] = b[h*48+d];
    }
  } else if (idx < NW + 147456) {
    pwb[idx - NW] = f2bf(pw_w[idx - NW]);
  } else if (idx < NW + 2*147456) {
    wob[idx - NW - 147456] = f2bf(wo[idx - NW - 147456]);
  }
}

// ---------------- k1: depthwise 3x3 conv (+dw_b) -> t bf16 ----------------
__global__ __launch_bounds__(256) void k1_dw(
    const float* __restrict__ x, const float* __restrict__ dw_w,
    const float* __restrict__ dw_b, u16* __restrict__ t)
{
  int idx = blockIdx.x*256 + threadIdx.x;   // 786432 threads
  int c4 = idx % 96; int rest = idx / 96;
  int jg = rest & 15; rest >>= 4;
  int i = rest & 63; int b = rest >> 6;
  int c0 = c4*4, j0 = jg*4;
  float wf[36];
  {
    const float4* wp = (const float4*)(dw_w + c0*9);
    #pragma unroll
    for (int k=0;k<9;k++){
      float4 v = wp[k];
      wf[4*k] = v.x; wf[4*k+1] = v.y; wf[4*k+2] = v.z; wf[4*k+3] = v.w;
    }
  }
  float4 bias = *(const float4*)(dw_b + c0);
  float acc[4][4];
  #pragma unroll
  for (int tk=0;tk<4;tk++){
    acc[tk][0]=bias.x; acc[tk][1]=bias.y; acc[tk][2]=bias.z; acc[tk][3]=bias.w;
  }
  const float* xb = x + ((size_t)b<<12)*384;
  #pragma unroll
  for (int di=-1; di<=1; ++di){
    int ii = i+di; if ((unsigned)ii >= 64u) continue;
    #pragma unroll
    for (int dj=-1; dj<=4; ++dj){
      int jj = j0+dj; if ((unsigned)jj >= 64u) continue;
      float4 xv = *(const float4*)(xb + (size_t)((ii<<6)+jj)*384 + c0);
      #pragma unroll
      for (int tk=0;tk<4;tk++){
        const int dd = dj - tk;
        if (dd < -1 || dd > 1) continue;
        const int tap = (di+1)*3 + (dd+1);
        acc[tk][0] = fmaf(xv.x, wf[0*9+tap], acc[tk][0]);
        acc[tk][1] = fmaf(xv.y, wf[1*9+tap], acc[tk][1]);
        acc[tk][2] = fmaf(xv.z, wf[2*9+tap], acc[tk][2]);
        acc[tk][3] = fmaf(xv.w, wf[3*9+tap], acc[tk][3]);
      }
    }
  }
  int mbase = (b<<12) + (i<<6) + j0;
  #pragma unroll
  for (int tk=0;tk<4;tk++){
    ushort4 o; o.x=f2bf(acc[tk][0]); o.y=f2bf(acc[tk][1]);
    o.z=f2bf(acc[tk][2]); o.w=f2bf(acc[tk][3]);
    *(ushort4*)(t + (size_t)(mbase+tk)*384 + c0) = o;
  }
}

// ---------------- k2: xm = bf16( x + t @ pw^T + pw_b ) --------------------
__global__ __launch_bounds__(256) void k2_gemm_pw(
    const u16* __restrict__ t, const u16* __restrict__ pwb,
    const float* __restrict__ x, const float* __restrict__ pw_b,
    u16* __restrict__ xm)
{
  __shared__ __align__(16) u16 As[128*64];
  __shared__ __align__(16) u16 Bs[128*64];
  const int m0 = blockIdx.x * 128;
  const int n0 = blockIdx.y * 128;
  const int tid = threadIdx.x, w = tid>>6, l = tid&63;
  const int lc = l & 15, hi = l >> 4;
  const int osw = ((l&7) ^ (l>>3))*16;   // swizzled chunk within row's 128B
  const f32x4 zf = {0.f,0.f,0.f,0.f};
  f32x4 acc[4][4];
  #pragma unroll
  for (int i=0;i<4;i++)
    #pragma unroll
    for (int j=0;j<4;j++) acc[i][j] = zf;

  for (int k0=0; k0<384; k0+=64) {
    #pragma unroll
    for (int i=0;i<4;i++){
      int ch = w*4+i;
      int row = ch*8 + (l>>3);
      gll16((const char*)t   + ((size_t)(m0+row)*384 + k0)*2 + osw, (char*)As + ch*1024);
      gll16((const char*)pwb + ((size_t)(n0+row)*384 + k0)*2 + osw, (char*)Bs + ch*1024);
    }
    __syncthreads();
    const int wr = (w>>1)*64, wc = (w&1)*64;
    #pragma unroll
    for (int kk=0; kk<64; kk+=32){
      const int sc = (((kk>>3)+hi) ^ (lc&7))*8;
      bf16x8 a[4], bb[4];
      #pragma unroll
      for (int i=0;i<4;i++) a[i]  = *(const bf16x8*)&As[(wr + i*16 + lc)*64 + sc];
      #pragma unroll
      for (int j=0;j<4;j++) bb[j] = *(const bf16x8*)&Bs[(wc + j*16 + lc)*64 + sc];
      #pragma unroll
      for (int i=0;i<4;i++)
        #pragma unroll
        for (int j=0;j<4;j++)
          acc[i][j] = MFMA16(a[i], bb[j], acc[i][j]);
    }
    __syncthreads();
  }
  const int wr=(w>>1)*64, wc=(w&1)*64;
  #pragma unroll
  for (int j=0;j<4;j++){
    int n = n0 + wc + j*16 + lc;
    float bias = pw_b[n];
    #pragma unroll
    for (int i=0;i<4;i++)
      #pragma unroll
      for (int r=0;r<4;r++){
        int m = m0 + wr + i*16 + hi*4 + r;
        float v = acc[i][j][r] + x[(size_t)m*384 + n] + bias;
        xm[(size_t)m*384 + n] = f2bf(v);
      }
  }
}

// ---------------- k3: fused QKVG GEMM + activations + kv/ksum partials ----
// R8 structure; atomics replaced by per-block partial slabs (no contention).
__global__ __launch_bounds__(256) void k3_gemm_qkvg(
    const u16* __restrict__ xm, const u16* __restrict__ wpack,
    const float* __restrict__ bpack, const float* __restrict__ temperature,
    u16* __restrict__ qh, float* __restrict__ pkv, float* __restrict__ pks)
{
  __shared__ __align__(16) u16 smem[40960];   // 80KB
  const int m0 = blockIdx.x * 128;
  const int h  = blockIdx.y;
  const int tid = threadIdx.x, w = tid>>6, l = tid&63;
  const int lc = l & 15, hi = l >> 4;
  const int osw = ((l&7) ^ (l>>3))*16;
  const f32x4 zf = {0.f,0.f,0.f,0.f};
  f32x4 acc[2][12];
  #pragma unroll
  for (int i=0;i<2;i++)
    #pragma unroll
    for (int j=0;j<12;j++) acc[i][j] = zf;

  const int arow = (w*4)*8 + (l>>3);
  const int brow = (w*6)*8 + (l>>3);

  #define K3_STAGE(T, BUF) do {                                                \
    const int k0_ = (T)*64;                                                    \
    char* Ab_ = (char*)(smem + (BUF)*8192);                                    \
    char* Bb_ = (char*)(smem + 16384 + (BUF)*12288);                           \
    _Pragma("unroll")                                                          \
    for (int i=0;i<4;i++)                                                      \
      gll16((const char*)xm + ((size_t)(m0+arow+i*8)*384 + k0_)*2 + osw,       \
            Ab_ + (w*4+i)*1024);                                               \
    _Pragma("unroll")                                                          \
    for (int i=0;i<6;i++)                                                      \
      gll16((const char*)wpack + ((size_t)(h*192+brow+i*8)*384 + k0_)*2 + osw, \
            Bb_ + (w*6+i)*1024);                                               \
  } while(0)

  K3_STAGE(0, 0);
  __syncthreads();
  int cur = 0;
  const int rbase = w*32;
  for (int t=0; t<6; ++t){
    if (t < 5) K3_STAGE(t+1, cur^1);
    const u16* Ab = smem + cur*8192;
    const u16* Bb = smem + 16384 + cur*12288;
    #pragma unroll
    for (int kk=0; kk<64; kk+=32){
      const int sc = (((kk>>3)+hi) ^ (lc&7))*8;
      bf16x8 a0 = *(const bf16x8*)&Ab[(rbase +      lc)*64 + sc];
      bf16x8 a1 = *(const bf16x8*)&Ab[(rbase + 16 + lc)*64 + sc];
      #pragma unroll
      for (int j=0;j<12;j++){
        bf16x8 bb = *(const bf16x8*)&Bb[(j*16 + lc)*64 + sc];
        acc[0][j] = MFMA16(a0, bb, acc[0][j]);
        acc[1][j] = MFMA16(a1, bb, acc[1][j]);
      }
    }
    __syncthreads();
    cur ^= 1;
  }
  #undef K3_STAGE

  // ---- epilogue ----
  const float tq = temperature[h];
  const int b = m0 >> 12;
  const int mtile = (m0 >> 7) & 31;
  const size_t bh = (size_t)b*8 + h;
  const int bb0 = h*192;
  float biasq[3], biask[3], biasv[3], biasg[3];
  #pragma unroll
  for (int j=0;j<3;j++){
    biasq[j] = bpack[bb0       + j*16 + lc];
    biask[j] = bpack[bb0 + 48  + j*16 + lc];
    biasv[j] = bpack[bb0 + 96  + j*16 + lc];
    biasg[j] = bpack[bb0 + 144 + j*16 + lc];
  }
  u16* kT = smem;          // [48][136]
  u16* vT = smem + 6528;   // [48][136]
  float ksp[3] = {0.f, 0.f, 0.f};

  #pragma unroll
  for (int i=0;i<2;i++){
    ushort4 kst[3], vst[3];
    #pragma unroll
    for (int r=0;r<4;r++){
      int m = m0 + w*32 + i*16 + hi*4 + r;
      int n = m & 4095;
      size_t rowq = (bh*4096 + n)*64;
      // q: no max-sub needed (exact num/den cancellation)
      float q0=(acc[i][0][r]+biasq[0])*tq;
      float q1=(acc[i][1][r]+biasq[1])*tq;
      float q2=(acc[i][2][r]+biasq[2])*tq;
      qh[rowq +      lc] = f2bf(expf(q0));
      qh[rowq + 16 + lc] = f2bf(expf(q1));
      qh[rowq + 32 + lc] = f2bf(expf(q2));
      qh[rowq + 48 + lc] = 0;
      float s0=acc[i][3][r]+biask[0];
      float s1=acc[i][4][r]+biask[1];
      float s2=acc[i][5][r]+biask[2];
      float mk = fmaxf(s0,fmaxf(s1,s2));
      mk = fmaxf(mk, __shfl_xor(mk,1,64));
      mk = fmaxf(mk, __shfl_xor(mk,2,64));
      mk = fmaxf(mk, __shfl_xor(mk,4,64));
      mk = fmaxf(mk, __shfl_xor(mk,8,64));
      float k0e = expf(s0-mk), k1e = expf(s1-mk), k2e = expf(s2-mk);
      ksp[0] += k0e; ksp[1] += k1e; ksp[2] += k2e;
      u16 kq0=f2bf(k0e), kq1=f2bf(k1e), kq2=f2bf(k2e);
      u16 vq[3];
      #pragma unroll
      for (int j=0;j<3;j++){
        float vv = acc[i][6+j][r] + biasv[j];
        float gg = acc[i][9+j][r] + biasg[j];
        float sg = 1.f/(1.f + expf(-gg));
        vq[j] = f2bf(vv*sg);
      }
      if (r==0){ kst[0].x=kq0; kst[1].x=kq1; kst[2].x=kq2; vst[0].x=vq[0]; vst[1].x=vq[1]; vst[2].x=vq[2]; }
      if (r==1){ kst[0].y=kq0; kst[1].y=kq1; kst[2].y=kq2; vst[0].y=vq[0]; vst[1].y=vq[1]; vst[2].y=vq[2]; }
      if (r==2){ kst[0].z=kq0; kst[1].z=kq1; kst[2].z=kq2; vst[0].z=vq[0]; vst[1].z=vq[1]; vst[2].z=vq[2]; }
      if (r==3){ kst[0].w=kq0; kst[1].w=kq1; kst[2].w=kq2; vst[0].w=vq[0]; vst[1].w=vq[1]; vst[2].w=vq[2]; }
    }
    int mb = w*32 + i*16 + hi*4;
    #pragma unroll
    for (int j=0;j<3;j++){
      *(ushort4*)&kT[(j*16+lc)*136 + mb] = kst[j];
      *(ushort4*)&vT[(j*16+lc)*136 + mb] = vst[j];
    }
  }
  __syncthreads();

  bf16x8 af[3], bfv[3];
  #pragma unroll
  for (int da=0;da<3;da++) af[da]  = *(const bf16x8*)&kT[(da*16+lc)*136 + w*32 + hi*8];
  #pragma unroll
  for (int eb=0;eb<3;eb++) bfv[eb] = *(const bf16x8*)&vT[(eb*16+lc)*136 + w*32 + hi*8];
  f32x4 a2[3][3];
  #pragma unroll
  for (int da=0;da<3;da++)
    #pragma unroll
    for (int eb=0;eb<3;eb++)
      a2[da][eb] = MFMA16(af[da], bfv[eb], zf);
  __syncthreads();
  float* pb = (float*)smem + w*2304;
  #pragma unroll
  for (int da=0;da<3;da++)
    #pragma unroll
    for (int eb=0;eb<3;eb++)
      #pragma unroll
      for (int rr=0;rr<4;rr++)
        pb[(da*16 + hi*4 + rr)*48 + eb*16 + lc] = a2[da][eb][rr];
  __syncthreads();
  {
    float* p0 = (float*)smem;
    float* dst = pkv + ((size_t)bh*32 + mtile)*2304;
    for (int u=tid; u<2304; u+=256)
      dst[u] = p0[u] + p0[2304+u] + p0[4608+u] + p0[6912+u];
  }
  #pragma unroll
  for (int j=0;j<3;j++){
    ksp[j] += __shfl_xor(ksp[j],16,64);
    ksp[j] += __shfl_xor(ksp[j],32,64);
  }
  if (hi==0 && w==0){
    float* ds = pks + ((size_t)bh*32 + mtile)*48;
    ds[lc] = ksp[0]; ds[16+lc] = ksp[1]; ds[32+lc] = ksp[2];
  }
  // other waves' ksp also hold per-wave sums; combine via LDS
  __syncthreads();
  {
    float* kr = (float*)smem;           // [4][48]
    if (hi==0){ kr[w*48+lc]=ksp[0]; kr[w*48+16+lc]=ksp[1]; kr[w*48+32+lc]=ksp[2]; }
    __syncthreads();
    if (tid < 48){
      float* ds = pks + ((size_t)bh*32 + mtile)*48;
      ds[tid] = kr[tid] + kr[48+tid] + kr[96+tid] + kr[144+tid];
    }
  }
}

// ---------------- k5: reduce partials -> kvp[e][d] bf16 (64x64, ksum row48)
__global__ __launch_bounds__(256) void k5_red(
    const float* __restrict__ pkv, const float* __restrict__ pks,
    u16* __restrict__ kvp)
{
  __shared__ float sm[2304];
  __shared__ float ks[48];
  int bh = blockIdx.x, tid = threadIdx.x;
  const float* base = pkv + (size_t)bh*32*2304;
  for (int u=tid; u<2304; u+=256){
    float v = 0.f;
    #pragma unroll
    for (int m=0;m<32;m++) v += base[(size_t)m*2304 + u];
    sm[u] = v;
  }
  if (tid < 48){
    const float* bk = pks + (size_t)bh*32*48 + tid;
    float v = 0.f;
    #pragma unroll
    for (int m=0;m<32;m++) v += bk[m*48];
    ks[tid] = v;
  }
  __syncthreads();
  for (int u=tid; u<4096; u+=256){
    int e = u >> 6, d = u & 63;
    float v = 0.f;
    if (e < 48 && d < 48)       v = sm[d*48 + e];
    else if (e == 48 && d < 48) v = ks[d];
    kvp[((size_t)bh*64 + e)*64 + d] = f2bf(v);
  }
}

// ---------------- k6: num/den -> a_hat bf16 [B,N,C] -----------------------
__global__ __launch_bounds__(256) void k6_num(
    const u16* __restrict__ qh, const u16* __restrict__ kvp, u16* __restrict__ ah)
{
  __shared__ __align__(16) u16 As[256*64]; // 32KB
  __shared__ __align__(16) u16 Bs[64*64];  // 8KB
  const int bh = blockIdx.x >> 4, nc = blockIdx.x & 15;
  const int tid = threadIdx.x, w = tid>>6, l = tid&63;
  const int lc = l & 15, hi = l >> 4;
  const f32x4 zf = {0.f,0.f,0.f,0.f};
  const u16* gq = qh + ((size_t)bh*4096 + nc*256)*64;
  #pragma unroll
  for (int it=0; it<8; ++it){
    int s = it*256 + tid;
    int row = s>>3, c = s&7, g = c ^ (row&7);
    ((uint4*)As)[s] = *(const uint4*)(gq + (size_t)row*64 + g*8);
  }
  const u16* gk = kvp + (size_t)bh*4096;
  #pragma unroll
  for (int it=0; it<2; ++it){
    int s = it*256 + tid;
    int row = s>>3, c = s&7, g = c ^ (row&7);
    ((uint4*)Bs)[s] = *(const uint4*)(gk + (size_t)row*64 + g*8);
  }
  __syncthreads();
  f32x4 acc[4][4];
  #pragma unroll
  for (int i=0;i<4;i++)
    #pragma unroll
    for (int j=0;j<4;j++) acc[i][j] = zf;
  const int rbase = w*64;
  #pragma unroll
  for (int kk=0; kk<64; kk+=32){
    const int sc = (((kk>>3)+hi) ^ (lc&7))*8;
    bf16x8 a[4], bb[4];
    #pragma unroll
    for (int i=0;i<4;i++) a[i]  = *(const bf16x8*)&As[(rbase + i*16 + lc)*64 + sc];
    #pragma unroll
    for (int j=0;j<4;j++) bb[j] = *(const bf16x8*)&Bs[(j*16 + lc)*64 + sc];
    #pragma unroll
    for (int i=0;i<4;i++)
      #pragma unroll
      for (int j=0;j<4;j++)
        acc[i][j] = MFMA16(a[i], bb[j], acc[i][j]);
  }
  const int b = bh >> 3, h = bh & 7;
  #pragma unroll
  for (int i=0;i<4;i++){
    #pragma unroll
    for (int r=0;r<4;r++){
      float den = __shfl(acc[i][3][r], l & 48, 64) + EPSF;
      float rd = 1.f/den;
      int n = nc*256 + rbase + i*16 + hi*4 + r;
      size_t ob = ((size_t)b*4096 + n)*384 + h*48;
      ah[ob +      lc] = f2bf(acc[i][0][r]*rd);
      ah[ob + 16 + lc] = f2bf(acc[i][1][r]*rd);
      ah[ob + 32 + lc] = f2bf(acc[i][2][r]*rd);
    }
  }
}

// ---------------- k7: out = a_hat @ wo^T + bo (fp32) ----------------------
__global__ __launch_bounds__(256) void k7_gemm_out(
    const u16* __restrict__ ah, const u16* __restrict__ wob,
    const float* __restrict__ bo, float* __restrict__ out)
{
  __shared__ __align__(16) u16 As[128*64];
  __shared__ __align__(16) u16 Bs[128*64];
  const int m0 = blockIdx.x * 128;
  const int n0 = blockIdx.y * 128;
  const int tid = threadIdx.x, w = tid>>6, l = tid&63;
  const int lc = l & 15, hi = l >> 4;
  const int osw = ((l&7) ^ (l>>3))*16;
  const f32x4 zf = {0.f,0.f,0.f,0.f};
  f32x4 acc[4][4];
  #pragma unroll
  for (int i=0;i<4;i++)
    #pragma unroll
    for (int j=0;j<4;j++) acc[i][j] = zf;

  for (int k0=0; k0<384; k0+=64) {
    #pragma unroll
    for (int i=0;i<4;i++){
      int ch = w*4+i;
      int row = ch*8 + (l>>3);
      gll16((const char*)ah  + ((size_t)(m0+row)*384 + k0)*2 + osw, (char*)As + ch*1024);
      gll16((const char*)wob + ((size_t)(n0+row)*384 + k0)*2 + osw, (char*)Bs + ch*1024);
    }
    __syncthreads();
    const int wr = (w>>1)*64, wc = (w&1)*64;
    #pragma unroll
    for (int kk=0; kk<64; kk+=32){
      const int sc = (((kk>>3)+hi) ^ (lc&7))*8;
      bf16x8 a[4], bb[4];
      #pragma unroll
      for (int i=0;i<4;i++) a[i]  = *(const bf16x8*)&As[(wr + i*16 + lc)*64 + sc];
      #pragma unroll
      for (int j=0;j<4;j++) bb[j] = *(const bf16x8*)&Bs[(wc + j*16 + lc)*64 + sc];
      #pragma unroll
      for (int i=0;i<4;i++)
        #pragma unroll
        for (int j=0;j<4;j++)
          acc[i][j] = MFMA16(a[i], bb[j], acc[i][j]);
    }
    __syncthreads();
  }
  const int wr=(w>>1)*64, wc=(w&1)*64;
  #pragma unroll
  for (int j=0;j<4;j++){
    int n = n0 + wc + j*16 + lc;
    float bias = bo[n];
    #pragma unroll
    for (int i=0;i<4;i++)
      #pragma unroll
      for (int r=0;r<4;r++){
        int m = m0 + wr + i*16 + hi*4 + r;
        out[(size_t)m*384 + n] = acc[i][j][r] + bias;
      }
  }
}

extern "C" void kernel_launch(void* const* d_in, const int* in_sizes, int n_in,
                              void* d_out, int out_size, void* d_ws, size_t ws_size,
                              hipStream_t stream)
{
  const float* x    = (const float*)d_in[0];
  const float* wq   = (const float*)d_in[1];
  const float* bq   = (const float*)d_in[2];
  const float* wk   = (const float*)d_in[3];
  const float* bk   = (const float*)d_in[4];
  const float* wv   = (const float*)d_in[5];
  const float* bv   = (const float*)d_in[6];
  const float* wg   = (const float*)d_in[7];
  const float* bg   = (const float*)d_in[8];
  const float* wo   = (const float*)d_in[9];
  const float* bo   = (const float*)d_in[10];
  const float* temp = (const float*)d_in[11];
  const float* dw_w = (const float*)d_in[12];
  const float* dw_b = (const float*)d_in[13];
  const float* pw_w = (const float*)d_in[14];
  const float* pw_b = (const float*)d_in[15];
  float* out = (float*)d_out;
  char* ws = (char*)d_ws;

  // t region (25165824 B) triple-used sequentially:
  //   k1 writes t -> k2 reads t -> k3/k5 use it as pkv/pks -> k6 writes ah
  u16*   t       = (u16*)(ws + 0);
  float* pkv     = (float*)(ws + 0);          // 18874368  [64][32][2304] f32
  float* pks     = (float*)(ws + 18874368);   // 393216    [64][32][48] f32
  u16*   ah      = (u16*)(ws + 0);            // 25165824  (k6 out, k7 in)
  u16*   xm      = (u16*)(ws + 25165824);     // 25165824
  u16*   qh      = (u16*)(ws + 50331648);     // 33554432  [B,H,N,64]
  u16*   wpack   = (u16*)(ws + 83886080);     // 1179648
  u16*   pwb     = (u16*)(ws + 85065728);     // 294912
  u16*   wob     = (u16*)(ws + 85360640);     // 294912
  float* bpack   = (float*)(ws + 85655552);   // 6144
  u16*   kvp     = (u16*)(ws + 85661696);     // 524288  [64][64][64] bf16

  k0_prep<<<3456, 256, 0, stream>>>(wq,bq,wk,bk,wv,bv,wg,bg,pw_w,wo,
                                    wpack,pwb,wob,bpack);
  k1_dw<<<3072, 256, 0, stream>>>(x, dw_w, dw_b, t);
  k2_gemm_pw<<<dim3(256,3), 256, 0, stream>>>(t, pwb, x, pw_b, xm);
  k3_gemm_qkvg<<<dim3(256,8), 256, 0, stream>>>(xm, wpack, bpack, temp, qh, pkv, pks);
  k5_red<<<64, 256, 0, stream>>>(pkv, pks, kvp);
  k6_num<<<1024, 256, 0, stream>>>(qh, kvp, ah);
  k7_gemm_out<<<dim3(256,3), 256, 0, stream>>>(ah, wob, bo, out);
}

// Round 10
// 174.648 us; speedup vs baseline: 1.3192x; 1.0684x over previous
//
#include <hip/hip_runtime.h>
#include <math.h>

#define EPSF 1e-6f

typedef __attribute__((ext_vector_type(8))) short bf16x8;
typedef __attribute__((ext_vector_type(4))) float f32x4;
typedef unsigned short u16;
typedef unsigned int u32;

#define MFMA16(a,b,c) __builtin_amdgcn_mfma_f32_16x16x32_bf16((a),(b),(c),0,0,0)

__device__ __forceinline__ u16 f2bf(float f){
  u32 x = __builtin_bit_cast(u32, f);
  u32 r = (x + 0x7fffu + ((x >> 16) & 1u)) >> 16;
  return (u16)r;
}
__device__ __forceinline__ void gll16(const void* g, void* l){
  __builtin_amdgcn_global_load_lds(
      (const __attribute__((address_space(1))) u32*)g,
      (__attribute__((address_space(3))) u32*)l, 16, 0, 0);
}

// ---------------- k0: pack weights to bf16 ---------------------------------
__global__ __launch_bounds__(256) void k0_prep(
    const float* __restrict__ wq, const float* __restrict__ bq,
    const float* __restrict__ wk, const float* __restrict__ bk,
    const float* __restrict__ wv, const float* __restrict__ bv,
    const float* __restrict__ wg, const float* __restrict__ bg,
    const float* __restrict__ pw_w, const float* __restrict__ wo,
    u16* __restrict__ wpack, u16* __restrict__ pwb, u16* __restrict__ wob,
    float* __restrict__ bpack)
{
  int idx = blockIdx.x*256 + threadIdx.x;
  const int NW = 1536*384;
  if (idx < NW) {
    int r = idx / 384, c = idx - r*384;
    int h = r / 192, s = (r % 192)/48, d = r % 48;
    const float* w = (s==0)?wq:(s==1)?wk:(s==2)?wv:wg;
    wpack[idx] = f2bf(w[(h*48+d)*384 + c]);
    if (c==0){
      const float* b = (s==0)?bq:(s==1)?bk:(s==2)?bv:bg;
      bpack[r] = b[h*48+d];
    }
  } else if (idx < NW + 147456) {
    pwb[idx - NW] = f2bf(pw_w[idx - NW]);
  } else if (idx < NW + 2*147456) {
    wob[idx - NW - 147456] = f2bf(wo[idx - NW - 147456]);
  }
}

// ---------------- k1: depthwise 3x3 conv (+dw_b) -> t bf16 ----------------
__global__ __launch_bounds__(256) void k1_dw(
    const float* __restrict__ x, const float* __restrict__ dw_w,
    const float* __restrict__ dw_b, u16* __restrict__ t)
{
  int idx = blockIdx.x*256 + threadIdx.x;   // 786432 threads
  int c4 = idx % 96; int rest = idx / 96;
  int jg = rest & 15; rest >>= 4;
  int i = rest & 63; int b = rest >> 6;
  int c0 = c4*4, j0 = jg*4;
  float wf[36];
  {
    const float4* wp = (const float4*)(dw_w + c0*9);
    #pragma unroll
    for (int k=0;k<9;k++){
      float4 v = wp[k];
      wf[4*k] = v.x; wf[4*k+1] = v.y; wf[4*k+2] = v.z; wf[4*k+3] = v.w;
    }
  }
  float4 bias = *(const float4*)(dw_b + c0);
  float acc[4][4];
  #pragma unroll
  for (int tk=0;tk<4;tk++){
    acc[tk][0]=bias.x; acc[tk][1]=bias.y; acc[tk][2]=bias.z; acc[tk][3]=bias.w;
  }
  const float* xb = x + ((size_t)b<<12)*384;
  #pragma unroll
  for (int di=-1; di<=1; ++di){
    int ii = i+di; if ((unsigned)ii >= 64u) continue;
    #pragma unroll
    for (int dj=-1; dj<=4; ++dj){
      int jj = j0+dj; if ((unsigned)jj >= 64u) continue;
      float4 xv = *(const float4*)(xb + (size_t)((ii<<6)+jj)*384 + c0);
      #pragma unroll
      for (int tk=0;tk<4;tk++){
        const int dd = dj - tk;
        if (dd < -1 || dd > 1) continue;
        const int tap = (di+1)*3 + (dd+1);
        acc[tk][0] = fmaf(xv.x, wf[0*9+tap], acc[tk][0]);
        acc[tk][1] = fmaf(xv.y, wf[1*9+tap], acc[tk][1]);
        acc[tk][2] = fmaf(xv.z, wf[2*9+tap], acc[tk][2]);
        acc[tk][3] = fmaf(xv.w, wf[3*9+tap], acc[tk][3]);
      }
    }
  }
  int mbase = (b<<12) + (i<<6) + j0;
  #pragma unroll
  for (int tk=0;tk<4;tk++){
    ushort4 o; o.x=f2bf(acc[tk][0]); o.y=f2bf(acc[tk][1]);
    o.z=f2bf(acc[tk][2]); o.w=f2bf(acc[tk][3]);
    *(ushort4*)(t + (size_t)(mbase+tk)*384 + c0) = o;
  }
}

// ---------------- k2: xm = bf16( x + t @ pw^T + pw_b ), dbuf prefetch -----
__global__ __launch_bounds__(256) void k2_gemm_pw(
    const u16* __restrict__ t, const u16* __restrict__ pwb,
    const float* __restrict__ x, const float* __restrict__ pw_b,
    u16* __restrict__ xm)
{
  __shared__ __align__(16) u16 smem[32768];  // 64KB: A dbuf 2x16KB, B dbuf 2x16KB
  const int m0 = blockIdx.x * 128;
  const int n0 = blockIdx.y * 128;
  const int tid = threadIdx.x, w = tid>>6, l = tid&63;
  const int lc = l & 15, hi = l >> 4;
  const int osw = ((l&7) ^ (l>>3))*16;
  const f32x4 zf = {0.f,0.f,0.f,0.f};
  f32x4 acc[4][4];
  #pragma unroll
  for (int i=0;i<4;i++)
    #pragma unroll
    for (int j=0;j<4;j++) acc[i][j] = zf;

  const int srow = (w*4)*8 + (l>>3);

  #define K2_STAGE(T, BUF) do {                                            \
    const int k0_ = (T)*64;                                                \
    char* Ab_ = (char*)(smem + (BUF)*8192);                                \
    char* Bb_ = (char*)(smem + 16384 + (BUF)*8192);                        \
    _Pragma("unroll")                                                      \
    for (int i=0;i<4;i++){                                                 \
      gll16((const char*)t   + ((size_t)(m0+srow+i*8)*384 + k0_)*2 + osw,  \
            Ab_ + (w*4+i)*1024);                                           \
      gll16((const char*)pwb + ((size_t)(n0+srow+i*8)*384 + k0_)*2 + osw,  \
            Bb_ + (w*4+i)*1024);                                           \
    }                                                                      \
  } while(0)

  K2_STAGE(0, 0);
  __syncthreads();
  int cur = 0;
  for (int t_=0; t_<6; ++t_){
    if (t_ < 5) K2_STAGE(t_+1, cur^1);
    const u16* As = smem + cur*8192;
    const u16* Bs = smem + 16384 + cur*8192;
    const int wr = (w>>1)*64, wc = (w&1)*64;
    #pragma unroll
    for (int kk=0; kk<64; kk+=32){
      const int sc = (((kk>>3)+hi) ^ (lc&7))*8;
      bf16x8 a[4], bb[4];
      #pragma unroll
      for (int i=0;i<4;i++) a[i]  = *(const bf16x8*)&As[(wr + i*16 + lc)*64 + sc];
      #pragma unroll
      for (int j=0;j<4;j++) bb[j] = *(const bf16x8*)&Bs[(wc + j*16 + lc)*64 + sc];
      #pragma unroll
      for (int i=0;i<4;i++)
        #pragma unroll
        for (int j=0;j<4;j++)
          acc[i][j] = MFMA16(a[i], bb[j], acc[i][j]);
    }
    __syncthreads();
    cur ^= 1;
  }
  #undef K2_STAGE
  const int wr=(w>>1)*64, wc=(w&1)*64;
  #pragma unroll
  for (int j=0;j<4;j++){
    int n = n0 + wc + j*16 + lc;
    float bias = pw_b[n];
    #pragma unroll
    for (int i=0;i<4;i++)
      #pragma unroll
      for (int r=0;r<4;r++){
        int m = m0 + wr + i*16 + hi*4 + r;
        float v = acc[i][j][r] + x[(size_t)m*384 + n] + bias;
        xm[(size_t)m*384 + n] = f2bf(v);
      }
  }
}

// ---------------- k3: fused QKVG GEMM + activations + kv/ksum partials ----
__global__ __launch_bounds__(256) void k3_gemm_qkvg(
    const u16* __restrict__ xm, const u16* __restrict__ wpack,
    const float* __restrict__ bpack, const float* __restrict__ temperature,
    u16* __restrict__ qh, float* __restrict__ pkv, float* __restrict__ pks)
{
  __shared__ __align__(16) u16 smem[40960];   // 80KB
  const int m0 = blockIdx.x * 128;
  const int h  = blockIdx.y;
  const int tid = threadIdx.x, w = tid>>6, l = tid&63;
  const int lc = l & 15, hi = l >> 4;
  const int osw = ((l&7) ^ (l>>3))*16;
  const f32x4 zf = {0.f,0.f,0.f,0.f};
  f32x4 acc[2][12];
  #pragma unroll
  for (int i=0;i<2;i++)
    #pragma unroll
    for (int j=0;j<12;j++) acc[i][j] = zf;

  const int arow = (w*4)*8 + (l>>3);
  const int brow = (w*6)*8 + (l>>3);

  #define K3_STAGE(T, BUF) do {                                                \
    const int k0_ = (T)*64;                                                    \
    char* Ab_ = (char*)(smem + (BUF)*8192);                                    \
    char* Bb_ = (char*)(smem + 16384 + (BUF)*12288);                           \
    _Pragma("unroll")                                                          \
    for (int i=0;i<4;i++)                                                      \
      gll16((const char*)xm + ((size_t)(m0+arow+i*8)*384 + k0_)*2 + osw,       \
            Ab_ + (w*4+i)*1024);                                               \
    _Pragma("unroll")                                                          \
    for (int i=0;i<6;i++)                                                      \
      gll16((const char*)wpack + ((size_t)(h*192+brow+i*8)*384 + k0_)*2 + osw, \
            Bb_ + (w*6+i)*1024);                                               \
  } while(0)

  K3_STAGE(0, 0);
  __syncthreads();
  int cur = 0;
  const int rbase = w*32;
  for (int t=0; t<6; ++t){
    if (t < 5) K3_STAGE(t+1, cur^1);
    const u16* Ab = smem + cur*8192;
    const u16* Bb = smem + 16384 + cur*12288;
    #pragma unroll
    for (int kk=0; kk<64; kk+=32){
      const int sc = (((kk>>3)+hi) ^ (lc&7))*8;
      bf16x8 a0 = *(const bf16x8*)&Ab[(rbase +      lc)*64 + sc];
      bf16x8 a1 = *(const bf16x8*)&Ab[(rbase + 16 + lc)*64 + sc];
      #pragma unroll
      for (int j=0;j<12;j++){
        bf16x8 bb = *(const bf16x8*)&Bb[(j*16 + lc)*64 + sc];
        acc[0][j] = MFMA16(a0, bb, acc[0][j]);
        acc[1][j] = MFMA16(a1, bb, acc[1][j]);
      }
    }
    __syncthreads();
    cur ^= 1;
  }
  #undef K3_STAGE

  // ---- epilogue (fast-math transcendentals) ----
  const float tq = temperature[h];
  const int b = m0 >> 12;
  const int mtile = (m0 >> 7) & 31;
  const size_t bh = (size_t)b*8 + h;
  const int bb0 = h*192;
  float biasq[3], biask[3], biasv[3], biasg[3];
  #pragma unroll
  for (int j=0;j<3;j++){
    biasq[j] = bpack[bb0       + j*16 + lc];
    biask[j] = bpack[bb0 + 48  + j*16 + lc];
    biasv[j] = bpack[bb0 + 96  + j*16 + lc];
    biasg[j] = bpack[bb0 + 144 + j*16 + lc];
  }
  u16* kT = smem;          // [48][136]
  u16* vT = smem + 6528;   // [48][136]
  float ksp[3] = {0.f, 0.f, 0.f};

  #pragma unroll
  for (int i=0;i<2;i++){
    ushort4 kst[3], vst[3];
    #pragma unroll
    for (int r=0;r<4;r++){
      int m = m0 + w*32 + i*16 + hi*4 + r;
      int n = m & 4095;
      size_t rowq = (bh*4096 + n)*48;
      float q0=(acc[i][0][r]+biasq[0])*tq;
      float q1=(acc[i][1][r]+biasq[1])*tq;
      float q2=(acc[i][2][r]+biasq[2])*tq;
      qh[rowq +      lc] = f2bf(__expf(q0));
      qh[rowq + 16 + lc] = f2bf(__expf(q1));
      qh[rowq + 32 + lc] = f2bf(__expf(q2));
      float s0=acc[i][3][r]+biask[0];
      float s1=acc[i][4][r]+biask[1];
      float s2=acc[i][5][r]+biask[2];
      float mk = fmaxf(s0,fmaxf(s1,s2));
      mk = fmaxf(mk, __shfl_xor(mk,1,64));
      mk = fmaxf(mk, __shfl_xor(mk,2,64));
      mk = fmaxf(mk, __shfl_xor(mk,4,64));
      mk = fmaxf(mk, __shfl_xor(mk,8,64));
      float k0e = __expf(s0-mk), k1e = __expf(s1-mk), k2e = __expf(s2-mk);
      ksp[0] += k0e; ksp[1] += k1e; ksp[2] += k2e;
      u16 kq0=f2bf(k0e), kq1=f2bf(k1e), kq2=f2bf(k2e);
      u16 vq[3];
      #pragma unroll
      for (int j=0;j<3;j++){
        float vv = acc[i][6+j][r] + biasv[j];
        float gg = acc[i][9+j][r] + biasg[j];
        float sg = __builtin_amdgcn_rcpf(1.f + __expf(-gg));
        vq[j] = f2bf(vv*sg);
      }
      if (r==0){ kst[0].x=kq0; kst[1].x=kq1; kst[2].x=kq2; vst[0].x=vq[0]; vst[1].x=vq[1]; vst[2].x=vq[2]; }
      if (r==1){ kst[0].y=kq0; kst[1].y=kq1; kst[2].y=kq2; vst[0].y=vq[0]; vst[1].y=vq[1]; vst[2].y=vq[2]; }
      if (r==2){ kst[0].z=kq0; kst[1].z=kq1; kst[2].z=kq2; vst[0].z=vq[0]; vst[1].z=vq[1]; vst[2].z=vq[2]; }
      if (r==3){ kst[0].w=kq0; kst[1].w=kq1; kst[2].w=kq2; vst[0].w=vq[0]; vst[1].w=vq[1]; vst[2].w=vq[2]; }
    }
    int mb = w*32 + i*16 + hi*4;
    #pragma unroll
    for (int j=0;j<3;j++){
      *(ushort4*)&kT[(j*16+lc)*136 + mb] = kst[j];
      *(ushort4*)&vT[(j*16+lc)*136 + mb] = vst[j];
    }
  }
  __syncthreads();

  bf16x8 af[3], bfv[3];
  #pragma unroll
  for (int da=0;da<3;da++) af[da]  = *(const bf16x8*)&kT[(da*16+lc)*136 + w*32 + hi*8];
  #pragma unroll
  for (int eb=0;eb<3;eb++) bfv[eb] = *(const bf16x8*)&vT[(eb*16+lc)*136 + w*32 + hi*8];
  f32x4 a2[3][3];
  #pragma unroll
  for (int da=0;da<3;da++)
    #pragma unroll
    for (int eb=0;eb<3;eb++)
      a2[da][eb] = MFMA16(af[da], bfv[eb], zf);
  __syncthreads();
  float* pb = (float*)smem + w*2304;
  #pragma unroll
  for (int da=0;da<3;da++)
    #pragma unroll
    for (int eb=0;eb<3;eb++)
      #pragma unroll
      for (int rr=0;rr<4;rr++)
        pb[(da*16 + hi*4 + rr)*48 + eb*16 + lc] = a2[da][eb][rr];
  __syncthreads();
  {
    float* p0 = (float*)smem;
    float* dst = pkv + ((size_t)bh*32 + mtile)*2304;
    for (int u=tid; u<2304; u+=256)
      dst[u] = p0[u] + p0[2304+u] + p0[4608+u] + p0[6912+u];
  }
  #pragma unroll
  for (int j=0;j<3;j++){
    ksp[j] += __shfl_xor(ksp[j],16,64);
    ksp[j] += __shfl_xor(ksp[j],32,64);
  }
  __syncthreads();
  {
    float* kr = (float*)smem;           // [4][48]
    if (hi==0){ kr[w*48+lc]=ksp[0]; kr[w*48+16+lc]=ksp[1]; kr[w*48+32+lc]=ksp[2]; }
    __syncthreads();
    if (tid < 48){
      float* ds = pks + ((size_t)bh*32 + mtile)*48;
      ds[tid] = kr[tid] + kr[48+tid] + kr[96+tid] + kr[144+tid];
    }
  }
}

// ---------------- k5: reduce partials -> kvp[e][d] bf16 (64x64, ksum row48)
__global__ __launch_bounds__(256) void k5_red(
    const float* __restrict__ pkv, const float* __restrict__ pks,
    u16* __restrict__ kvp)
{
  __shared__ float sm[2304];
  __shared__ float ks[48];
  int bh = blockIdx.x, tid = threadIdx.x;
  const float* base = pkv + (size_t)bh*32*2304;
  for (int u=tid; u<2304; u+=256){
    float v = 0.f;
    #pragma unroll
    for (int m=0;m<32;m++) v += base[(size_t)m*2304 + u];
    sm[u] = v;
  }
  if (tid < 48){
    const float* bk = pks + (size_t)bh*32*48 + tid;
    float v = 0.f;
    #pragma unroll
    for (int m=0;m<32;m++) v += bk[m*48];
    ks[tid] = v;
  }
  __syncthreads();
  for (int u=tid; u<4096; u+=256){
    int e = u >> 6, d = u & 63;
    float v = 0.f;
    if (e < 48 && d < 48)       v = sm[d*48 + e];
    else if (e == 48 && d < 48) v = ks[d];
    kvp[((size_t)bh*64 + e)*64 + d] = f2bf(v);
  }
}

// ---------------- k6: num/den -> a_hat bf16 [B,N,C] (qh 48-wide) ----------
__global__ __launch_bounds__(256) void k6_num(
    const u16* __restrict__ qh, const u16* __restrict__ kvp, u16* __restrict__ ah)
{
  __shared__ __align__(16) u16 As[256*64]; // 32KB
  __shared__ __align__(16) u16 Bs[64*64];  // 8KB
  const int bh = blockIdx.x >> 4, nc = blockIdx.x & 15;
  const int tid = threadIdx.x, w = tid>>6, l = tid&63;
  const int lc = l & 15, hi = l >> 4;
  const f32x4 zf = {0.f,0.f,0.f,0.f};
  const uint4 z4 = {0,0,0,0};
  const u16* gq = qh + ((size_t)bh*4096 + nc*256)*48;
  #pragma unroll
  for (int it=0; it<8; ++it){
    int s = it*256 + tid;
    int row = s>>3, c = s&7, g = c ^ (row&7);
    ((uint4*)As)[s] = (g < 6) ? *(const uint4*)(gq + (size_t)row*48 + g*8) : z4;
  }
  const u16* gk = kvp + (size_t)bh*4096;
  #pragma unroll
  for (int it=0; it<2; ++it){
    int s = it*256 + tid;
    int row = s>>3, c = s&7, g = c ^ (row&7);
    ((uint4*)Bs)[s] = *(const uint4*)(gk + (size_t)row*64 + g*8);
  }
  __syncthreads();
  f32x4 acc[4][4];
  #pragma unroll
  for (int i=0;i<4;i++)
    #pragma unroll
    for (int j=0;j<4;j++) acc[i][j] = zf;
  const int rbase = w*64;
  #pragma unroll
  for (int kk=0; kk<64; kk+=32){
    const int sc = (((kk>>3)+hi) ^ (lc&7))*8;
    bf16x8 a[4], bb[4];
    #pragma unroll
    for (int i=0;i<4;i++) a[i]  = *(const bf16x8*)&As[(rbase + i*16 + lc)*64 + sc];
    #pragma unroll
    for (int j=0;j<4;j++) bb[j] = *(const bf16x8*)&Bs[(j*16 + lc)*64 + sc];
    #pragma unroll
    for (int i=0;i<4;i++)
      #pragma unroll
      for (int j=0;j<4;j++)
        acc[i][j] = MFMA16(a[i], bb[j], acc[i][j]);
  }
  const int b = bh >> 3, h = bh & 7;
  #pragma unroll
  for (int i=0;i<4;i++){
    #pragma unroll
    for (int r=0;r<4;r++){
      float den = __shfl(acc[i][3][r], l & 48, 64) + EPSF;
      float rd = __builtin_amdgcn_rcpf(den);
      int n = nc*256 + rbase + i*16 + hi*4 + r;
      size_t ob = ((size_t)b*4096 + n)*384 + h*48;
      ah[ob +      lc] = f2bf(acc[i][0][r]*rd);
      ah[ob + 16 + lc] = f2bf(acc[i][1][r]*rd);
      ah[ob + 32 + lc] = f2bf(acc[i][2][r]*rd);
    }
  }
}

// ---------------- k7: out = a_hat @ wo^T + bo (fp32), dbuf prefetch -------
__global__ __launch_bounds__(256) void k7_gemm_out(
    const u16* __restrict__ ah, const u16* __restrict__ wob,
    const float* __restrict__ bo, float* __restrict__ out)
{
  __shared__ __align__(16) u16 smem[32768];  // 64KB dbuf
  const int m0 = blockIdx.x * 128;
  const int n0 = blockIdx.y * 128;
  const int tid = threadIdx.x, w = tid>>6, l = tid&63;
  const int lc = l & 15, hi = l >> 4;
  const int osw = ((l&7) ^ (l>>3))*16;
  const f32x4 zf = {0.f,0.f,0.f,0.f};
  f32x4 acc[4][4];
  #pragma unroll
  for (int i=0;i<4;i++)
    #pragma unroll
    for (int j=0;j<4;j++) acc[i][j] = zf;

  const int srow = (w*4)*8 + (l>>3);

  #define K7_STAGE(T, BUF) do {                                            \
    const int k0_ = (T)*64;                                                \
    char* Ab_ = (char*)(smem + (BUF)*8192);                                \
    char* Bb_ = (char*)(smem + 16384 + (BUF)*8192);                        \
    _Pragma("unroll")                                                      \
    for (int i=0;i<4;i++){                                                 \
      gll16((const char*)ah  + ((size_t)(m0+srow+i*8)*384 + k0_)*2 + osw,  \
            Ab_ + (w*4+i)*1024);                                           \
      gll16((const char*)wob + ((size_t)(n0+srow+i*8)*384 + k0_)*2 + osw,  \
            Bb_ + (w*4+i)*1024);                                           \
    }                                                                      \
  } while(0)

  K7_STAGE(0, 0);
  __syncthreads();
  int cur = 0;
  for (int t_=0; t_<6; ++t_){
    if (t_ < 5) K7_STAGE(t_+1, cur^1);
    const u16* As = smem + cur*8192;
    const u16* Bs = smem + 16384 + cur*8192;
    const int wr = (w>>1)*64, wc = (w&1)*64;
    #pragma unroll
    for (int kk=0; kk<64; kk+=32){
      const int sc = (((kk>>3)+hi) ^ (lc&7))*8;
      bf16x8 a[4], bb[4];
      #pragma unroll
      for (int i=0;i<4;i++) a[i]  = *(const bf16x8*)&As[(wr + i*16 + lc)*64 + sc];
      #pragma unroll
      for (int j=0;j<4;j++) bb[j] = *(const bf16x8*)&Bs[(wc + j*16 + lc)*64 + sc];
      #pragma unroll
      for (int i=0;i<4;i++)
        #pragma unroll
        for (int j=0;j<4;j++)
          acc[i][j] = MFMA16(a[i], bb[j], acc[i][j]);
    }
    __syncthreads();
    cur ^= 1;
  }
  #undef K7_STAGE
  const int wr=(w>>1)*64, wc=(w&1)*64;
  #pragma unroll
  for (int j=0;j<4;j++){
    int n = n0 + wc + j*16 + lc;
    float bias = bo[n];
    #pragma unroll
    for (int i=0;i<4;i++)
      #pragma unroll
      for (int r=0;r<4;r++){
        int m = m0 + wr + i*16 + hi*4 + r;
        out[(size_t)m*384 + n] = acc[i][j][r] + bias;
      }
  }
}

extern "C" void kernel_launch(void* const* d_in, const int* in_sizes, int n_in,
                              void* d_out, int out_size, void* d_ws, size_t ws_size,
                              hipStream_t stream)
{
  const float* x    = (const float*)d_in[0];
  const float* wq   = (const float*)d_in[1];
  const float* bq   = (const float*)d_in[2];
  const float* wk   = (const float*)d_in[3];
  const float* bk   = (const float*)d_in[4];
  const float* wv   = (const float*)d_in[5];
  const float* bv   = (const float*)d_in[6];
  const float* wg   = (const float*)d_in[7];
  const float* bg   = (const float*)d_in[8];
  const float* wo   = (const float*)d_in[9];
  const float* bo   = (const float*)d_in[10];
  const float* temp = (const float*)d_in[11];
  const float* dw_w = (const float*)d_in[12];
  const float* dw_b = (const float*)d_in[13];
  const float* pw_w = (const float*)d_in[14];
  const float* pw_b = (const float*)d_in[15];
  float* out = (float*)d_out;
  char* ws = (char*)d_ws;

  u16*   t       = (u16*)(ws + 0);
  float* pkv     = (float*)(ws + 0);          // 18874368  [64][32][2304] f32
  float* pks     = (float*)(ws + 18874368);   // 393216    [64][32][48] f32
  u16*   ah      = (u16*)(ws + 0);            // 25165824  (k6 out, k7 in)
  u16*   xm      = (u16*)(ws + 25165824);     // 25165824
  u16*   qh      = (u16*)(ws + 50331648);     // 25165824  [B,H,N,48]
  u16*   wpack   = (u16*)(ws + 83886080);     // 1179648
  u16*   pwb     = (u16*)(ws + 85065728);     // 294912
  u16*   wob     = (u16*)(ws + 85360640);     // 294912
  float* bpack   = (float*)(ws + 85655552);   // 6144
  u16*   kvp     = (u16*)(ws + 85661696);     // 524288  [64][64][64] bf16

  k0_prep<<<3456, 256, 0, stream>>>(wq,bq,wk,bk,wv,bv,wg,bg,pw_w,wo,
                                    wpack,pwb,wob,bpack);
  k1_dw<<<3072, 256, 0, stream>>>(x, dw_w, dw_b, t);
  k2_gemm_pw<<<dim3(256,3), 256, 0, stream>>>(t, pwb, x, pw_b, xm);
  k3_gemm_qkvg<<<dim3(256,8), 256, 0, stream>>>(xm, wpack, bpack, temp, qh, pkv, pks);
  k5_red<<<64, 256, 0, stream>>>(pkv, pks, kvp);
  k6_num<<<1024, 256, 0, stream>>>(qh, kvp, ah);
  k7_gemm_out<<<dim3(256,3), 256, 0, stream>>>(ah, wob, bo, out);
}